// Round 12
// baseline (94.679 us; speedup 1.0000x reference)
//
#include <hip/hip_runtime.h>

typedef _Float16 f16x8 __attribute__((ext_vector_type(8)));
typedef __fp16 h16x2 __attribute__((ext_vector_type(2)));
typedef float f32x4 __attribute__((ext_vector_type(4)));
typedef float f32x16 __attribute__((ext_vector_type(16)));

#define GF(r) ((((r)&3)) ^ (((r)>>2)&3))
#define LOG2E 1.44269504088896f

#define GLD16(gp, lp) __builtin_amdgcn_global_load_lds( \
    (const __attribute__((address_space(1))) void*)(gp), \
    (__attribute__((address_space(3))) void*)(lp), 16, 0, 0)

// ---------------- kernel 1: fused x->fp16 + copy, W->W^T fp16 ----------------
__global__ void cvt_all_kernel(const float4* __restrict__ x4, f16x8* __restrict__ xh,
                               float4* __restrict__ xc,
                               const float* __restrict__ Wq, const float* __restrict__ Wk,
                               const float* __restrict__ Wv, _Float16* __restrict__ wt) {
    const int blk = blockIdx.x;
    if (blk < 2048) {
        int i = blk * 256 + threadIdx.x;
        float4 a = x4[2 * i], b = x4[2 * i + 1];
        xc[2 * i] = a;
        xc[2 * i + 1] = b;
        f16x8 h;
        h[0] = (_Float16)a.x; h[1] = (_Float16)a.y; h[2] = (_Float16)a.z; h[3] = (_Float16)a.w;
        h[4] = (_Float16)b.x; h[5] = (_Float16)b.y; h[6] = (_Float16)b.z; h[7] = (_Float16)b.w;
        xh[i] = h;
    } else {
        int j = (blk - 2048) * 256 + threadIdx.x;   // 3*512*512 = 786432
        int mat = j >> 18;
        int r = (j >> 9) & 511;
        int n = j & 511;
        const float* W = (mat == 0) ? Wq : ((mat == 1) ? Wk : Wv);
        float v = W[r * 512 + n];
        wt[(size_t)mat * 262144 + (size_t)n * 512 + r] = (_Float16)v;
    }
}

// ---------------- kernel 3: QKV GEMM (fp16 MFMA, 3-buf counted-vmcnt) ----------
__global__ __launch_bounds__(256, 2) void gemm_qkv(
    const _Float16* __restrict__ xh, const _Float16* __restrict__ wt,
    _Float16* __restrict__ qh, _Float16* __restrict__ kh, _Float16* __restrict__ vt) {
    __shared__ __align__(16) char gsm[49152];   // 3 bufs x (8KB A + 8KB B)
    const int mat = blockIdx.y;
    const _Float16* wp = wt + (size_t)mat * 262144;
    const int mtile = blockIdx.x >> 2, ntile = blockIdx.x & 3;
    const int tid = threadIdx.x, lane = tid & 63;
    const int g = lane >> 4, c = lane & 15;
    const int wid = tid >> 6, wm = wid >> 1, wn = wid & 1;

    f32x4 acc[4][4];
#pragma unroll
    for (int i = 0; i < 4; ++i)
#pragma unroll
        for (int j = 0; j < 4; ++j) acc[i][j] = (f32x4){0.f, 0.f, 0.f, 0.f};

    const int row0 = tid >> 2, p0 = tid & 3;

    auto GSTAGE = [&](int buf, int ks) {
        _Float16* la_ = (_Float16*)(gsm + buf * 16384);
        _Float16* lb_ = (_Float16*)(gsm + buf * 16384 + 8192);
        int r = row0, pp = p0 ^ GF(r);
        GLD16(xh + (size_t)(mtile * 128 + r) * 512 + ks * 32 + pp * 8, &la_[tid * 8]);
        GLD16(wp + (size_t)(ntile * 128 + r) * 512 + ks * 32 + pp * 8, &lb_[tid * 8]);
        r = 64 + row0; pp = p0 ^ GF(r);
        GLD16(xh + (size_t)(mtile * 128 + r) * 512 + ks * 32 + pp * 8, &la_[(256 + tid) * 8]);
        GLD16(wp + (size_t)(ntile * 128 + r) * 512 + ks * 32 + pp * 8, &lb_[(256 + tid) * 8]);
    };

    auto GTILE = [&](int ks) {
        const _Float16* la = (const _Float16*)(gsm + (ks % 3) * 16384);
        const _Float16* lb = (const _Float16*)(gsm + (ks % 3) * 16384 + 8192);
        f16x8 af[4], bf[4];
#pragma unroll
        for (int i = 0; i < 4; ++i) {
            int ra = wm * 64 + i * 16 + c;
            af[i] = *(const f16x8*)&la[ra * 32 + ((g ^ GF(ra)) * 8)];
            int rb = wn * 64 + i * 16 + c;
            bf[i] = *(const f16x8*)&lb[rb * 32 + ((g ^ GF(rb)) * 8)];
        }
        __builtin_amdgcn_s_setprio(1);
#pragma unroll
        for (int mi = 0; mi < 4; ++mi)
#pragma unroll
            for (int ni = 0; ni < 4; ++ni)
                acc[mi][ni] = __builtin_amdgcn_mfma_f32_16x16x32_f16(af[mi], bf[ni], acc[mi][ni], 0, 0, 0);
        __builtin_amdgcn_s_setprio(0);
    };

    GSTAGE(0, 0); GSTAGE(1, 1);
#pragma unroll 1
    for (int ks = 0; ks < 14; ++ks) {
        asm volatile("s_waitcnt vmcnt(4)" ::: "memory");
        __builtin_amdgcn_s_barrier();
        __builtin_amdgcn_sched_barrier(0);
        GSTAGE((ks + 2) % 3, ks + 2);
        GTILE(ks);
    }
    asm volatile("s_waitcnt vmcnt(4)" ::: "memory");
    __builtin_amdgcn_s_barrier();
    GTILE(14);
    asm volatile("s_waitcnt vmcnt(0)" ::: "memory");
    __builtin_amdgcn_s_barrier();
    GTILE(15);

#pragma unroll
    for (int mi = 0; mi < 4; ++mi)
#pragma unroll
        for (int ni = 0; ni < 4; ++ni)
#pragma unroll
            for (int r = 0; r < 4; ++r) {
                int m = mtile * 128 + wm * 64 + mi * 16 + g * 4 + r;
                int n = ntile * 128 + wn * 64 + ni * 16 + c;
                _Float16 hv = (_Float16)acc[mi][ni][r];
                if (mat == 0) {
                    qh[(size_t)m * 512 + n] = hv;
                } else if (mat == 1) {
                    kh[(size_t)m * 512 + n] = hv;
                } else {
                    int h = n >> 6, d = n & 63, bb = m >> 11, s = m & 2047;
                    vt[(((size_t)h * 4 + bb) * 64 + d) * 2048 + s] = hv;
                }
            }
}

// ---------------- kernel 4: flash attention, 32-key tiles, 1-deep pipeline -----
// grid 512 x 512 threads: waves 0-3 keys 0-1023, waves 4-7 keys 1024-2047,
// 32 tiles of 32 keys; QK^T(t) overlaps softmax+PV(t-1); 4 LDS buffers,
// stage-2-ahead, counted vmcnt(2); flash-decode merge in LDS.
__global__ __launch_bounds__(512, 4) void attn_kernel(
    const _Float16* __restrict__ qh, const _Float16* __restrict__ kh,
    const _Float16* __restrict__ vt, float* __restrict__ out) {
    __shared__ __align__(16) char smem[65536];   // 4 bufs x [KA 4K|VA 4K|KB 4K|VB 4K]

    const int bid = blockIdx.x;
    const int xcd = bid & 7, idx = bid >> 3;     // idx 0..63
    const int hb = xcd * 4 + (idx >> 4);         // 0..31 (4 hb per XCD)
    const int qblk = idx & 15;                   // 0..15
    const int h = hb >> 2, b = hb & 3;
    const int tid = threadIdx.x, lane = tid & 63, wid = tid >> 6;  // wid 0..7
    const int qg = wid & 3, half = wid >> 2;
    const int q = lane & 31, hi = lane >> 5;

    const int qrow0 = qblk * 128 + qg * 32;
    const _Float16* qp = qh + ((size_t)b * 2048 + qrow0) * 512 + h * 64;
    const _Float16* kp = kh + (size_t)b * 2048 * 512 + h * 64;
    const _Float16* vp = vt + (size_t)hb * 64 * 2048;

    // staging (512 threads; tid>>8 selects which half this thread stages)
    const int sHalf = tid >> 8, stt = tid & 255;
    const int krow = stt >> 3;                                   // 0..31
    const int kch = (stt & 7) ^ ((krow ^ (krow >> 3)) & 7);
    const int vrow = stt >> 2;                                   // 0..63
    const int vch = (stt & 3) ^ ((vrow ^ (vrow >> 2)) & 3);

    auto STAGE = [&](int i) {   // caller guarantees i < 32
        char* base = smem + (i & 3) * 16384 + sHalf * 8192;
        const int kvt = sHalf * 32 + i;
        GLD16(kp + ((size_t)(kvt * 32 + krow) * 512) + kch * 8, (_Float16*)base + stt * 8);
        GLD16(vp + (size_t)vrow * 2048 + kvt * 32 + vch * 8, (_Float16*)(base + 4096) + stt * 8);
    };

    // Q fragments (MFMA B operand: col = q, k = kc*16 + hi*8 + j)
    f16x8 aQ[4];
#pragma unroll
    for (int kc = 0; kc < 4; ++kc)
        aQ[kc] = *(const f16x8*)(qp + (size_t)q * 512 + kc * 16 + hi * 8);

    float mrow = -1e30f, lrow = 0.f;   // lrow: LANE-PARTIAL
    f32x16 o0, o1;   // O^T d-blocks: row d = db*32 + (i&3)+8*(i>>2)+4*hi, col q
#pragma unroll
    for (int i = 0; i < 16; ++i) { o0[i] = 0.f; o1[i] = 0.f; }

    const h16x2 ONE2 = {(__fp16)1.0f, (__fp16)1.0f};
    const int swk = (q ^ (q >> 3)) & 7;
    const int swv0 = (q ^ (q >> 2)) & 3;
    const int swv1 = ((32 + q) ^ ((32 + q) >> 2)) & 3;

    auto KPTR = [&](int t) {
        return (const _Float16*)(smem + (t & 3) * 16384 + half * 8192);
    };
    auto VPTR = [&](int t) {
        return (const _Float16*)(smem + (t & 3) * 16384 + half * 8192 + 4096);
    };

    auto QKT = [&](const _Float16* kb, f32x16& s) {
        f32x16 z;
#pragma unroll
        for (int i = 0; i < 16; ++i) z[i] = 0.f;
        __builtin_amdgcn_s_setprio(1);
#pragma unroll
        for (int kc = 0; kc < 4; ++kc) {
            f16x8 ak = *(const f16x8*)&kb[q * 64 + (((2 * kc + hi) ^ swk) * 8)];
            z = __builtin_amdgcn_mfma_f32_32x32x16_f16(ak, aQ[kc], z, 0, 0, 0);
        }
        __builtin_amdgcn_s_setprio(0);
        s = z;
    };

    auto SMPV = [&](f32x16& s0, const _Float16* vb) {
        // deferred-max online softmax (16 lane-local values)
        float pm;
        {
            float m0 = fmaxf(fmaxf(fmaxf(s0[0], s0[1]), s0[2]), s0[3]);
            float m1 = fmaxf(fmaxf(fmaxf(s0[4], s0[5]), s0[6]), s0[7]);
            float m2 = fmaxf(fmaxf(fmaxf(s0[8], s0[9]), s0[10]), s0[11]);
            float m3 = fmaxf(fmaxf(fmaxf(s0[12], s0[13]), s0[14]), s0[15]);
            pm = fmaxf(fmaxf(m0, m1), fmaxf(m2, m3));
        }
        pm = fmaxf(pm, __shfl_xor(pm, 32));
        if (__any(pm > mrow + 8.0f)) {
            const float nm = fmaxf(mrow, pm);
            const float e = __builtin_amdgcn_exp2f((mrow - nm) * LOG2E);
            mrow = nm;
            lrow *= e;
            o0 *= e;
            o1 *= e;
        }
        const float nm2 = mrow * LOG2E;
#pragma unroll
        for (int i = 0; i < 16; ++i)
            s0[i] = __builtin_amdgcn_exp2f(fmaf(s0[i], LOG2E, -nm2));

        f16x8 pf[2];
        float rsA = 0.f, rsB = 0.f;
        {
            h16x2 p0 = __builtin_amdgcn_cvt_pkrtz(s0[0], s0[1]);
            h16x2 p1 = __builtin_amdgcn_cvt_pkrtz(s0[2], s0[3]);
            h16x2 p2 = __builtin_amdgcn_cvt_pkrtz(s0[4], s0[5]);
            h16x2 p3 = __builtin_amdgcn_cvt_pkrtz(s0[6], s0[7]);
            h16x2 p4 = __builtin_amdgcn_cvt_pkrtz(s0[8], s0[9]);
            h16x2 p5 = __builtin_amdgcn_cvt_pkrtz(s0[10], s0[11]);
            h16x2 p6 = __builtin_amdgcn_cvt_pkrtz(s0[12], s0[13]);
            h16x2 p7 = __builtin_amdgcn_cvt_pkrtz(s0[14], s0[15]);
            rsA = __builtin_amdgcn_fdot2(p0, ONE2, rsA, false);
            rsB = __builtin_amdgcn_fdot2(p1, ONE2, rsB, false);
            rsA = __builtin_amdgcn_fdot2(p2, ONE2, rsA, false);
            rsB = __builtin_amdgcn_fdot2(p3, ONE2, rsB, false);
            rsA = __builtin_amdgcn_fdot2(p4, ONE2, rsA, false);
            rsB = __builtin_amdgcn_fdot2(p5, ONE2, rsB, false);
            rsA = __builtin_amdgcn_fdot2(p6, ONE2, rsA, false);
            rsB = __builtin_amdgcn_fdot2(p7, ONE2, rsB, false);
            unsigned t0 = __builtin_bit_cast(unsigned, p0);
            unsigned t1 = __builtin_bit_cast(unsigned, p1);
            unsigned t2 = __builtin_bit_cast(unsigned, p2);
            unsigned t3 = __builtin_bit_cast(unsigned, p3);
            unsigned t4 = __builtin_bit_cast(unsigned, p4);
            unsigned t5 = __builtin_bit_cast(unsigned, p5);
            unsigned t6 = __builtin_bit_cast(unsigned, p6);
            unsigned t7 = __builtin_bit_cast(unsigned, p7);
            asm volatile("v_permlane32_swap_b32 %0, %1" : "+v"(t0), "+v"(t2));
            asm volatile("v_permlane32_swap_b32 %0, %1" : "+v"(t1), "+v"(t3));
            asm volatile("v_permlane32_swap_b32 %0, %1" : "+v"(t4), "+v"(t6));
            asm volatile("v_permlane32_swap_b32 %0, %1" : "+v"(t5), "+v"(t7));
            uint4 u0; u0.x = t0; u0.y = t1; u0.z = t2; u0.w = t3;
            uint4 u1; u1.x = t4; u1.y = t5; u1.z = t6; u1.w = t7;
            pf[0] = __builtin_bit_cast(f16x8, u0);
            pf[1] = __builtin_bit_cast(f16x8, u1);
        }
        lrow += rsA + rsB;

        __builtin_amdgcn_s_setprio(1);
#pragma unroll
        for (int ck = 0; ck < 2; ++ck) {
            f16x8 av0 = *(const f16x8*)&vb[q * 32 + (((2 * ck + hi) ^ swv0) * 8)];
            f16x8 av1 = *(const f16x8*)&vb[(32 + q) * 32 + (((2 * ck + hi) ^ swv1) * 8)];
            o0 = __builtin_amdgcn_mfma_f32_32x32x16_f16(av0, pf[ck], o0, 0, 0, 0);
            o1 = __builtin_amdgcn_mfma_f32_32x32x16_f16(av1, pf[ck], o1, 0, 0, 0);
        }
        __builtin_amdgcn_s_setprio(0);
    };

#define WAITBAR() do { \
    asm volatile("s_waitcnt vmcnt(2)" ::: "memory"); \
    __builtin_amdgcn_s_barrier(); \
    __builtin_amdgcn_sched_barrier(0); \
} while (0)

    f32x16 sA, sB;
    STAGE(0); STAGE(1);
    // peel tile 0: QK^T only
    WAITBAR();
    STAGE(2);
    QKT(KPTR(0), sA);

#pragma unroll 1
    for (int t = 1; t < 32; t += 2) {
        // tile t (odd): QK^T(t) overlaps SM+PV of tile t-1
        WAITBAR();
        if (t + 2 < 32) STAGE(t + 2);
        QKT(KPTR(t), sB);
        SMPV(sA, VPTR(t - 1));
        // tile t+1 (even): QK^T(t+1) overlaps SM+PV of tile t
        WAITBAR();
        if (t + 3 < 32) STAGE(t + 3);
        if (t + 1 < 32) QKT(KPTR(t + 1), sA);
        SMPV(sB, VPTR(t));
    }
    // loop handled QKT 0..31 and SMPV 0..31 (last SMPV(sB) = tile 31)

    // ---- flash-decode merge: half B hands (o, m, l) to half A via LDS ----
    lrow += __shfl_xor(lrow, 32);
    __builtin_amdgcn_s_barrier();   // all K/V reads done; smem reusable

    float* xg = (float*)smem + qg * 2112;   // 8448B per q-group
    if (half) {
#pragma unroll
        for (int i = 0; i < 16; ++i) {
            xg[i * 64 + lane] = o0[i];
            xg[(16 + i) * 64 + lane] = o1[i];
        }
        if (!hi) { xg[2048 + q] = mrow; xg[2080 + q] = lrow; }
    }
    __syncthreads();
    if (!half) {
        const float m_b = xg[2048 + q], l_b = xg[2080 + q];
        const float m = fmaxf(mrow, m_b);
        const float e_a = __builtin_amdgcn_exp2f((mrow - m) * LOG2E);
        const float e_b = __builtin_amdgcn_exp2f((m_b - m) * LOG2E);
        const float inv = 1.0f / (lrow * e_a + l_b * e_b);
        const float sa = e_a * inv, sb = e_b * inv;
#pragma unroll
        for (int i = 0; i < 16; ++i) {
            o0[i] = o0[i] * sa + xg[i * 64 + lane] * sb;
            o1[i] = o1[i] * sa + xg[(16 + i) * 64 + lane] * sb;
        }
        asm volatile("s_waitcnt lgkmcnt(0)" ::: "memory");
#pragma unroll
        for (int i = 0; i < 16; ++i) {
            int dr = (i & 3) + 8 * (i >> 2) + 4 * hi;
            xg[dr * 33 + q] = o0[i];
            xg[(32 + dr) * 33 + q] = o1[i];
        }
        __builtin_amdgcn_s_waitcnt(0);
        const int d0c = (lane & 15) * 4;
#pragma unroll
        for (int i2 = 0; i2 < 8; ++i2) {
            int qr = 4 * i2 + (lane >> 4);
            float4 v;
            v.x = xg[(d0c + 0) * 33 + qr];
            v.y = xg[(d0c + 1) * 33 + qr];
            v.z = xg[(d0c + 2) * 33 + qr];
            v.w = xg[(d0c + 3) * 33 + qr];
            *(float4*)(out + ((size_t)b * 2048 + qrow0 + qr) * 512 + h * 64 + d0c) = v;
        }
    }
#undef WAITBAR
}

extern "C" void kernel_launch(void* const* d_in, const int* in_sizes, int n_in,
                              void* d_out, int out_size, void* d_ws, size_t ws_size,
                              hipStream_t stream) {
    const float* x = (const float*)d_in[0];
    const float* Wq = (const float*)d_in[1];
    const float* Wk = (const float*)d_in[2];
    const float* Wv = (const float*)d_in[3];
    float* out = (float*)d_out;
    float* xcopy = out + 4194304;

    char* ws = (char*)d_ws;
    _Float16* xh = (_Float16*)ws;                          // 8 MB
    _Float16* wt = (_Float16*)(ws + (size_t)(10u << 20));  // 1.5 MB
    _Float16* qh = (_Float16*)(ws + (size_t)(12u << 20));  // 8 MB
    _Float16* kh = (_Float16*)(ws + (size_t)(20u << 20));  // 8 MB
    _Float16* vt = (_Float16*)(ws + (size_t)(28u << 20));  // 8 MB

    cvt_all_kernel<<<5120, 256, 0, stream>>>((const float4*)x, (f16x8*)xh, (float4*)xcopy,
                                             Wq, Wk, Wv, wt);
    gemm_qkv<<<dim3(256, 3), 256, 0, stream>>>(xh, wt, qh, kh, vt);
    attn_kernel<<<512, 512, 0, stream>>>(qh, kh, vt, out);
}

// Round 13
// 91.581 us; speedup vs baseline: 1.0338x; 1.0338x over previous
//
#include <hip/hip_runtime.h>

typedef _Float16 f16x8 __attribute__((ext_vector_type(8)));
typedef __fp16 h16x2 __attribute__((ext_vector_type(2)));
typedef float f32x4 __attribute__((ext_vector_type(4)));
typedef float f32x16 __attribute__((ext_vector_type(16)));

#define GF(r) ((((r)&3)) ^ (((r)>>2)&3))
#define LOG2E 1.44269504088896f

#define GLD16(gp, lp) __builtin_amdgcn_global_load_lds( \
    (const __attribute__((address_space(1))) void*)(gp), \
    (__attribute__((address_space(3))) void*)(lp), 16, 0, 0)

// ---------------- kernel 1: fused x->fp16 + copy, W->W^T fp16 ----------------
__global__ void cvt_all_kernel(const float4* __restrict__ x4, f16x8* __restrict__ xh,
                               float4* __restrict__ xc,
                               const float* __restrict__ Wq, const float* __restrict__ Wk,
                               const float* __restrict__ Wv, _Float16* __restrict__ wt) {
    const int blk = blockIdx.x;
    if (blk < 2048) {
        int i = blk * 256 + threadIdx.x;
        float4 a = x4[2 * i], b = x4[2 * i + 1];
        xc[2 * i] = a;
        xc[2 * i + 1] = b;
        f16x8 h;
        h[0] = (_Float16)a.x; h[1] = (_Float16)a.y; h[2] = (_Float16)a.z; h[3] = (_Float16)a.w;
        h[4] = (_Float16)b.x; h[5] = (_Float16)b.y; h[6] = (_Float16)b.z; h[7] = (_Float16)b.w;
        xh[i] = h;
    } else {
        int j = (blk - 2048) * 256 + threadIdx.x;   // 3*512*512 = 786432
        int mat = j >> 18;
        int r = (j >> 9) & 511;
        int n = j & 511;
        const float* W = (mat == 0) ? Wq : ((mat == 1) ? Wk : Wv);
        float v = W[r * 512 + n];
        wt[(size_t)mat * 262144 + (size_t)n * 512 + r] = (_Float16)v;
    }
}

// ---------------- kernel 3: QKV GEMM (fp16 MFMA, 3-buf counted-vmcnt) ----------
__global__ __launch_bounds__(256, 2) void gemm_qkv(
    const _Float16* __restrict__ xh, const _Float16* __restrict__ wt,
    _Float16* __restrict__ qh, _Float16* __restrict__ kh, _Float16* __restrict__ vt) {
    __shared__ __align__(16) char gsm[49152];   // 3 bufs x (8KB A + 8KB B)
    const int mat = blockIdx.y;
    const _Float16* wp = wt + (size_t)mat * 262144;
    const int mtile = blockIdx.x >> 2, ntile = blockIdx.x & 3;
    const int tid = threadIdx.x, lane = tid & 63;
    const int g = lane >> 4, c = lane & 15;
    const int wid = tid >> 6, wm = wid >> 1, wn = wid & 1;

    f32x4 acc[4][4];
#pragma unroll
    for (int i = 0; i < 4; ++i)
#pragma unroll
        for (int j = 0; j < 4; ++j) acc[i][j] = (f32x4){0.f, 0.f, 0.f, 0.f};

    const int row0 = tid >> 2, p0 = tid & 3;

    auto GSTAGE = [&](int buf, int ks) {
        _Float16* la_ = (_Float16*)(gsm + buf * 16384);
        _Float16* lb_ = (_Float16*)(gsm + buf * 16384 + 8192);
        int r = row0, pp = p0 ^ GF(r);
        GLD16(xh + (size_t)(mtile * 128 + r) * 512 + ks * 32 + pp * 8, &la_[tid * 8]);
        GLD16(wp + (size_t)(ntile * 128 + r) * 512 + ks * 32 + pp * 8, &lb_[tid * 8]);
        r = 64 + row0; pp = p0 ^ GF(r);
        GLD16(xh + (size_t)(mtile * 128 + r) * 512 + ks * 32 + pp * 8, &la_[(256 + tid) * 8]);
        GLD16(wp + (size_t)(ntile * 128 + r) * 512 + ks * 32 + pp * 8, &lb_[(256 + tid) * 8]);
    };

    auto GTILE = [&](int ks) {
        const _Float16* la = (const _Float16*)(gsm + (ks % 3) * 16384);
        const _Float16* lb = (const _Float16*)(gsm + (ks % 3) * 16384 + 8192);
        f16x8 af[4], bf[4];
#pragma unroll
        for (int i = 0; i < 4; ++i) {
            int ra = wm * 64 + i * 16 + c;
            af[i] = *(const f16x8*)&la[ra * 32 + ((g ^ GF(ra)) * 8)];
            int rb = wn * 64 + i * 16 + c;
            bf[i] = *(const f16x8*)&lb[rb * 32 + ((g ^ GF(rb)) * 8)];
        }
        __builtin_amdgcn_s_setprio(1);
#pragma unroll
        for (int mi = 0; mi < 4; ++mi)
#pragma unroll
            for (int ni = 0; ni < 4; ++ni)
                acc[mi][ni] = __builtin_amdgcn_mfma_f32_16x16x32_f16(af[mi], bf[ni], acc[mi][ni], 0, 0, 0);
        __builtin_amdgcn_s_setprio(0);
    };

    GSTAGE(0, 0); GSTAGE(1, 1);
#pragma unroll 1
    for (int ks = 0; ks < 14; ++ks) {
        asm volatile("s_waitcnt vmcnt(4)" ::: "memory");
        __builtin_amdgcn_s_barrier();
        __builtin_amdgcn_sched_barrier(0);
        GSTAGE((ks + 2) % 3, ks + 2);
        GTILE(ks);
    }
    asm volatile("s_waitcnt vmcnt(4)" ::: "memory");
    __builtin_amdgcn_s_barrier();
    GTILE(14);
    asm volatile("s_waitcnt vmcnt(0)" ::: "memory");
    __builtin_amdgcn_s_barrier();
    GTILE(15);

#pragma unroll
    for (int mi = 0; mi < 4; ++mi)
#pragma unroll
        for (int ni = 0; ni < 4; ++ni)
#pragma unroll
            for (int r = 0; r < 4; ++r) {
                int m = mtile * 128 + wm * 64 + mi * 16 + g * 4 + r;
                int n = ntile * 128 + wn * 64 + ni * 16 + c;
                _Float16 hv = (_Float16)acc[mi][ni][r];
                if (mat == 0) {
                    qh[(size_t)m * 512 + n] = hv;
                } else if (mat == 1) {
                    kh[(size_t)m * 512 + n] = hv;
                } else {
                    int h = n >> 6, d = n & 63, bb = m >> 11, s = m & 2047;
                    vt[(((size_t)h * 4 + bb) * 64 + d) * 2048 + s] = hv;
                }
            }
}

// ---------------- kernel 4: flash attention, 64-key tiles, phase-staggered -----
// grid 512 x 512 threads: waves 0-3 keys 0-1023 (order QKT;SMPV), waves 4-7 keys
// 1024-2047 (order SMPV(t-1);QKT(t)) -> each barrier interval mixes MFMA-heavy
// and VALU-heavy waves. 2 LDS buffer sets; flash-decode merge in LDS.
__global__ __launch_bounds__(512, 4) void attn_kernel(
    const _Float16* __restrict__ qh, const _Float16* __restrict__ kh,
    const _Float16* __restrict__ vt, float* __restrict__ out) {
    __shared__ __align__(16) char smem[65536];   // 2 sets x (K_A,V_A,K_B,V_B 8KB each)

    const int bid = blockIdx.x;
    const int xcd = bid & 7, idx = bid >> 3;     // idx 0..63
    const int hb = xcd * 4 + (idx >> 4);         // 0..31 (4 hb per XCD)
    const int qblk = idx & 15;                   // 0..15
    const int h = hb >> 2, b = hb & 3;
    const int tid = threadIdx.x, lane = tid & 63, wid = tid >> 6;  // wid 0..7
    const int qg = wid & 3, half = wid >> 2;
    const int q = lane & 31, hi = lane >> 5;

    const int qrow0 = qblk * 128 + qg * 32;
    const _Float16* qp = qh + ((size_t)b * 2048 + qrow0) * 512 + h * 64;
    const _Float16* kp = kh + (size_t)b * 2048 * 512 + h * 64;
    const _Float16* vp = vt + (size_t)hb * 64 * 2048;

    // staging: row = tid>>3 (0..63), slot = tid&7, src chunk = slot ^ swz(row)
    const int srow = tid >> 3;
    const int ssw = (tid & 7) ^ ((srow ^ (srow >> 3)) & 7);

    // stage both halves' tile i: half A -> kt=i, half B -> kt=16+i
    auto STAGE = [&](int i) {
        char* base = smem + (i & 1) * 32768;
        GLD16(kp + ((size_t)(i * 64 + srow) * 512) + ssw * 8, (_Float16*)(base) + tid * 8);
        GLD16(vp + (size_t)srow * 2048 + i * 64 + ssw * 8, (_Float16*)(base + 8192) + tid * 8);
        GLD16(kp + ((size_t)((16 + i) * 64 + srow) * 512) + ssw * 8, (_Float16*)(base + 16384) + tid * 8);
        GLD16(vp + (size_t)srow * 2048 + (16 + i) * 64 + ssw * 8, (_Float16*)(base + 24576) + tid * 8);
    };

    // Q fragments (MFMA B operand: col = q, k = kc*16 + hi*8 + j)
    f16x8 aQ[4];
#pragma unroll
    for (int kc = 0; kc < 4; ++kc)
        aQ[kc] = *(const f16x8*)(qp + (size_t)q * 512 + kc * 16 + hi * 8);

    float mrow = -1e30f, lrow = 0.f;   // lrow: LANE-PARTIAL
    f32x16 o0, o1;   // O^T d-blocks: row d = db*32 + (i&3)+8*(i>>2)+4*hi, col q
#pragma unroll
    for (int i = 0; i < 16; ++i) { o0[i] = 0.f; o1[i] = 0.f; }

    const h16x2 ONE2 = {(__fp16)1.0f, (__fp16)1.0f};
    const int swr0 = (q ^ (q >> 3)) & 7;                       // swz(row q)
    const int swr1 = ((32 + q) ^ ((32 + q) >> 3)) & 7;         // swz(row 32+q)

    auto KPTR = [&](int t) {
        return (const _Float16*)(smem + (t & 1) * 32768 + half * 16384);
    };

    auto QKT2 = [&](const _Float16* kb, f32x16& s0, f32x16& s1) {
        f32x16 z0, z1;
#pragma unroll
        for (int i = 0; i < 16; ++i) { z0[i] = 0.f; z1[i] = 0.f; }
        __builtin_amdgcn_s_setprio(1);
#pragma unroll
        for (int kc = 0; kc < 4; ++kc) {
            f16x8 ak0 = *(const f16x8*)&kb[q * 64 + (((2 * kc + hi) ^ swr0) * 8)];
            f16x8 ak1 = *(const f16x8*)&kb[(32 + q) * 64 + (((2 * kc + hi) ^ swr1) * 8)];
            z0 = __builtin_amdgcn_mfma_f32_32x32x16_f16(ak0, aQ[kc], z0, 0, 0, 0);
            z1 = __builtin_amdgcn_mfma_f32_32x32x16_f16(ak1, aQ[kc], z1, 0, 0, 0);
        }
        __builtin_amdgcn_s_setprio(0);
        s0 = z0; s1 = z1;
    };

    auto SMPV2 = [&](f32x16& s0, f32x16& s1, const _Float16* vb) {
        float pm;
        {
            float m0 = fmaxf(fmaxf(fmaxf(s0[0], s0[1]), s0[2]), s0[3]);
            float m1 = fmaxf(fmaxf(fmaxf(s0[4], s0[5]), s0[6]), s0[7]);
            float m2 = fmaxf(fmaxf(fmaxf(s0[8], s0[9]), s0[10]), s0[11]);
            float m3 = fmaxf(fmaxf(fmaxf(s0[12], s0[13]), s0[14]), s0[15]);
            float m4 = fmaxf(fmaxf(fmaxf(s1[0], s1[1]), s1[2]), s1[3]);
            float m5 = fmaxf(fmaxf(fmaxf(s1[4], s1[5]), s1[6]), s1[7]);
            float m6 = fmaxf(fmaxf(fmaxf(s1[8], s1[9]), s1[10]), s1[11]);
            float m7 = fmaxf(fmaxf(fmaxf(s1[12], s1[13]), s1[14]), s1[15]);
            float t0 = fmaxf(fmaxf(m0, m1), m2);
            float t1 = fmaxf(fmaxf(m3, m4), m5);
            float t2 = fmaxf(m6, m7);
            pm = fmaxf(fmaxf(t0, t1), t2);
        }
        pm = fmaxf(pm, __shfl_xor(pm, 32));
        if (__any(pm > mrow + 8.0f)) {
            const float nm = fmaxf(mrow, pm);
            const float e = __builtin_amdgcn_exp2f((mrow - nm) * LOG2E);
            mrow = nm;
            lrow *= e;
            o0 *= e;
            o1 *= e;
        }
        const float nm2 = mrow * LOG2E;

#pragma unroll
        for (int i = 0; i < 16; ++i)
            s0[i] = __builtin_amdgcn_exp2f(fmaf(s0[i], LOG2E, -nm2));
#pragma unroll
        for (int i = 0; i < 16; ++i)
            s1[i] = __builtin_amdgcn_exp2f(fmaf(s1[i], LOG2E, -nm2));

        f16x8 pf[4];
        float rsA = 0.f, rsB = 0.f;
#pragma unroll
        for (int kb2 = 0; kb2 < 2; ++kb2) {
            const f32x16& sv = kb2 ? s1 : s0;
            h16x2 p0 = __builtin_amdgcn_cvt_pkrtz(sv[0], sv[1]);
            h16x2 p1 = __builtin_amdgcn_cvt_pkrtz(sv[2], sv[3]);
            h16x2 p2 = __builtin_amdgcn_cvt_pkrtz(sv[4], sv[5]);
            h16x2 p3 = __builtin_amdgcn_cvt_pkrtz(sv[6], sv[7]);
            h16x2 p4 = __builtin_amdgcn_cvt_pkrtz(sv[8], sv[9]);
            h16x2 p5 = __builtin_amdgcn_cvt_pkrtz(sv[10], sv[11]);
            h16x2 p6 = __builtin_amdgcn_cvt_pkrtz(sv[12], sv[13]);
            h16x2 p7 = __builtin_amdgcn_cvt_pkrtz(sv[14], sv[15]);
            rsA = __builtin_amdgcn_fdot2(p0, ONE2, rsA, false);
            rsB = __builtin_amdgcn_fdot2(p1, ONE2, rsB, false);
            rsA = __builtin_amdgcn_fdot2(p2, ONE2, rsA, false);
            rsB = __builtin_amdgcn_fdot2(p3, ONE2, rsB, false);
            rsA = __builtin_amdgcn_fdot2(p4, ONE2, rsA, false);
            rsB = __builtin_amdgcn_fdot2(p5, ONE2, rsB, false);
            rsA = __builtin_amdgcn_fdot2(p6, ONE2, rsA, false);
            rsB = __builtin_amdgcn_fdot2(p7, ONE2, rsB, false);
            unsigned t0 = __builtin_bit_cast(unsigned, p0);
            unsigned t1 = __builtin_bit_cast(unsigned, p1);
            unsigned t2 = __builtin_bit_cast(unsigned, p2);
            unsigned t3 = __builtin_bit_cast(unsigned, p3);
            unsigned t4 = __builtin_bit_cast(unsigned, p4);
            unsigned t5 = __builtin_bit_cast(unsigned, p5);
            unsigned t6 = __builtin_bit_cast(unsigned, p6);
            unsigned t7 = __builtin_bit_cast(unsigned, p7);
            asm volatile("v_permlane32_swap_b32 %0, %1" : "+v"(t0), "+v"(t2));
            asm volatile("v_permlane32_swap_b32 %0, %1" : "+v"(t1), "+v"(t3));
            asm volatile("v_permlane32_swap_b32 %0, %1" : "+v"(t4), "+v"(t6));
            asm volatile("v_permlane32_swap_b32 %0, %1" : "+v"(t5), "+v"(t7));
            uint4 u0; u0.x = t0; u0.y = t1; u0.z = t2; u0.w = t3;
            uint4 u1; u1.x = t4; u1.y = t5; u1.z = t6; u1.w = t7;
            pf[2 * kb2 + 0] = __builtin_bit_cast(f16x8, u0);
            pf[2 * kb2 + 1] = __builtin_bit_cast(f16x8, u1);
        }
        lrow += rsA + rsB;

        __builtin_amdgcn_s_setprio(1);
#pragma unroll
        for (int ck = 0; ck < 4; ++ck) {
            f16x8 av0 = *(const f16x8*)&vb[q * 64 + (((2 * ck + hi) ^ swr0) * 8)];
            f16x8 av1 = *(const f16x8*)&vb[(32 + q) * 64 + (((2 * ck + hi) ^ swr1) * 8)];
            o0 = __builtin_amdgcn_mfma_f32_32x32x16_f16(av0, pf[ck], o0, 0, 0, 0);
            o1 = __builtin_amdgcn_mfma_f32_32x32x16_f16(av1, pf[ck], o1, 0, 0, 0);
        }
        __builtin_amdgcn_s_setprio(0);
    };

#define WAITBAR() do { \
    asm volatile("s_waitcnt vmcnt(0)" ::: "memory"); \
    __builtin_amdgcn_s_barrier(); \
    __builtin_amdgcn_sched_barrier(0); \
} while (0)

    f32x16 s0, s1;
    STAGE(0);
    if (half == 0) {
        // anchor order: QKT(t) then SMPV(t)
#pragma unroll 1
        for (int t = 0; t < 16; ++t) {
            WAITBAR();
            if (t < 15) STAGE(t + 1);
            QKT2(KPTR(t), s0, s1);
            SMPV2(s0, s1, KPTR(t) + 4096);
        }
    } else {
        // staggered order: SMPV(t-1) then QKT(t); s carried across barriers
        WAITBAR();
        STAGE(1);
        QKT2(KPTR(0), s0, s1);
#pragma unroll 1
        for (int t = 1; t < 16; ++t) {
            SMPV2(s0, s1, KPTR(t - 1) + 4096);
            WAITBAR();
            if (t < 15) STAGE(t + 1);
            QKT2(KPTR(t), s0, s1);
        }
        SMPV2(s0, s1, KPTR(15) + 4096);
    }

    // ---- flash-decode merge: half B hands (o, m, l) to half A via LDS ----
    lrow += __shfl_xor(lrow, 32);
    __builtin_amdgcn_s_barrier();   // all K/V reads done; smem reusable

    float* xg = (float*)smem + qg * 2112;   // 8448B per q-group
    if (half) {
#pragma unroll
        for (int i = 0; i < 16; ++i) {
            xg[i * 64 + lane] = o0[i];
            xg[(16 + i) * 64 + lane] = o1[i];
        }
        if (!hi) { xg[2048 + q] = mrow; xg[2080 + q] = lrow; }
    }
    __syncthreads();
    if (!half) {
        const float m_b = xg[2048 + q], l_b = xg[2080 + q];
        const float m = fmaxf(mrow, m_b);
        const float e_a = __builtin_amdgcn_exp2f((mrow - m) * LOG2E);
        const float e_b = __builtin_amdgcn_exp2f((m_b - m) * LOG2E);
        const float inv = 1.0f / (lrow * e_a + l_b * e_b);
        const float sa = e_a * inv, sb = e_b * inv;
#pragma unroll
        for (int i = 0; i < 16; ++i) {
            o0[i] = o0[i] * sa + xg[i * 64 + lane] * sb;
            o1[i] = o1[i] * sa + xg[(16 + i) * 64 + lane] * sb;
        }
        asm volatile("s_waitcnt lgkmcnt(0)" ::: "memory");
#pragma unroll
        for (int i = 0; i < 16; ++i) {
            int dr = (i & 3) + 8 * (i >> 2) + 4 * hi;
            xg[dr * 33 + q] = o0[i];
            xg[(32 + dr) * 33 + q] = o1[i];
        }
        __builtin_amdgcn_s_waitcnt(0);
        const int d0c = (lane & 15) * 4;
#pragma unroll
        for (int i2 = 0; i2 < 8; ++i2) {
            int qr = 4 * i2 + (lane >> 4);
            float4 v;
            v.x = xg[(d0c + 0) * 33 + qr];
            v.y = xg[(d0c + 1) * 33 + qr];
            v.z = xg[(d0c + 2) * 33 + qr];
            v.w = xg[(d0c + 3) * 33 + qr];
            *(float4*)(out + ((size_t)b * 2048 + qrow0 + qr) * 512 + h * 64 + d0c) = v;
        }
    }
#undef WAITBAR
}

extern "C" void kernel_launch(void* const* d_in, const int* in_sizes, int n_in,
                              void* d_out, int out_size, void* d_ws, size_t ws_size,
                              hipStream_t stream) {
    const float* x = (const float*)d_in[0];
    const float* Wq = (const float*)d_in[1];
    const float* Wk = (const float*)d_in[2];
    const float* Wv = (const float*)d_in[3];
    float* out = (float*)d_out;
    float* xcopy = out + 4194304;

    char* ws = (char*)d_ws;
    _Float16* xh = (_Float16*)ws;                          // 8 MB
    _Float16* wt = (_Float16*)(ws + (size_t)(10u << 20));  // 1.5 MB
    _Float16* qh = (_Float16*)(ws + (size_t)(12u << 20));  // 8 MB
    _Float16* kh = (_Float16*)(ws + (size_t)(20u << 20));  // 8 MB
    _Float16* vt = (_Float16*)(ws + (size_t)(28u << 20));  // 8 MB

    cvt_all_kernel<<<5120, 256, 0, stream>>>((const float4*)x, (f16x8*)xh, (float4*)xcopy,
                                             Wq, Wk, Wv, wt);
    gemm_qkv<<<dim3(256, 3), 256, 0, stream>>>(xh, wt, qh, kh, vt);
    attn_kernel<<<512, 512, 0, stream>>>(qh, kh, vt, out);
}

// Round 14
// 87.550 us; speedup vs baseline: 1.0814x; 1.0460x over previous
//
#include <hip/hip_runtime.h>

typedef _Float16 f16x8 __attribute__((ext_vector_type(8)));
typedef __fp16 h16x2 __attribute__((ext_vector_type(2)));
typedef float f32x4 __attribute__((ext_vector_type(4)));
typedef float f32x16 __attribute__((ext_vector_type(16)));

#define GF(r) ((((r)&3)) ^ (((r)>>2)&3))
#define LOG2E 1.44269504088896f

#define GLD16(gp, lp) __builtin_amdgcn_global_load_lds( \
    (const __attribute__((address_space(1))) void*)(gp), \
    (__attribute__((address_space(3))) void*)(lp), 16, 0, 0)

// ---------------- kernel 1: x -> fp16, W -> W^T fp16 (no xcopy; moved to attn) --
__global__ void cvt_all_kernel(const float4* __restrict__ x4, f16x8* __restrict__ xh,
                               const float* __restrict__ Wq, const float* __restrict__ Wk,
                               const float* __restrict__ Wv, _Float16* __restrict__ wt) {
    const int blk = blockIdx.x;
    if (blk < 2048) {
        int i = blk * 256 + threadIdx.x;
        float4 a = x4[2 * i], b = x4[2 * i + 1];
        f16x8 h;
        h[0] = (_Float16)a.x; h[1] = (_Float16)a.y; h[2] = (_Float16)a.z; h[3] = (_Float16)a.w;
        h[4] = (_Float16)b.x; h[5] = (_Float16)b.y; h[6] = (_Float16)b.z; h[7] = (_Float16)b.w;
        xh[i] = h;
    } else {
        int j = (blk - 2048) * 256 + threadIdx.x;   // 3*512*512 = 786432
        int mat = j >> 18;
        int r = (j >> 9) & 511;
        int n = j & 511;
        const float* W = (mat == 0) ? Wq : ((mat == 1) ? Wk : Wv);
        float v = W[r * 512 + n];
        wt[(size_t)mat * 262144 + (size_t)n * 512 + r] = (_Float16)v;
    }
}

// ---------------- kernel 2: QKV GEMM (fp16 MFMA, 3-buf counted-vmcnt) ----------
// Epilogue stages C through LDS (f16) for fully-coalesced 16B stores; vt path
// stages TRANSPOSED so [d][s] readback rows are contiguous.
__global__ __launch_bounds__(256, 2) void gemm_qkv(
    const _Float16* __restrict__ xh, const _Float16* __restrict__ wt,
    _Float16* __restrict__ qh, _Float16* __restrict__ kh, _Float16* __restrict__ vt) {
    __shared__ __align__(16) char gsm[49152];   // 3 bufs x (8KB A + 8KB B); epi reuse
    const int mat = blockIdx.y;
    const _Float16* wp = wt + (size_t)mat * 262144;
    const int mtile = blockIdx.x >> 2, ntile = blockIdx.x & 3;
    const int tid = threadIdx.x, lane = tid & 63;
    const int g = lane >> 4, c = lane & 15;
    const int wid = tid >> 6, wm = wid >> 1, wn = wid & 1;

    f32x4 acc[4][4];
#pragma unroll
    for (int i = 0; i < 4; ++i)
#pragma unroll
        for (int j = 0; j < 4; ++j) acc[i][j] = (f32x4){0.f, 0.f, 0.f, 0.f};

    const int row0 = tid >> 2, p0 = tid & 3;

    auto GSTAGE = [&](int buf, int ks) {
        _Float16* la_ = (_Float16*)(gsm + buf * 16384);
        _Float16* lb_ = (_Float16*)(gsm + buf * 16384 + 8192);
        int r = row0, pp = p0 ^ GF(r);
        GLD16(xh + (size_t)(mtile * 128 + r) * 512 + ks * 32 + pp * 8, &la_[tid * 8]);
        GLD16(wp + (size_t)(ntile * 128 + r) * 512 + ks * 32 + pp * 8, &lb_[tid * 8]);
        r = 64 + row0; pp = p0 ^ GF(r);
        GLD16(xh + (size_t)(mtile * 128 + r) * 512 + ks * 32 + pp * 8, &la_[(256 + tid) * 8]);
        GLD16(wp + (size_t)(ntile * 128 + r) * 512 + ks * 32 + pp * 8, &lb_[(256 + tid) * 8]);
    };

    auto GTILE = [&](int ks) {
        const _Float16* la = (const _Float16*)(gsm + (ks % 3) * 16384);
        const _Float16* lb = (const _Float16*)(gsm + (ks % 3) * 16384 + 8192);
        f16x8 af[4], bf[4];
#pragma unroll
        for (int i = 0; i < 4; ++i) {
            int ra = wm * 64 + i * 16 + c;
            af[i] = *(const f16x8*)&la[ra * 32 + ((g ^ GF(ra)) * 8)];
            int rb = wn * 64 + i * 16 + c;
            bf[i] = *(const f16x8*)&lb[rb * 32 + ((g ^ GF(rb)) * 8)];
        }
        __builtin_amdgcn_s_setprio(1);
#pragma unroll
        for (int mi = 0; mi < 4; ++mi)
#pragma unroll
            for (int ni = 0; ni < 4; ++ni)
                acc[mi][ni] = __builtin_amdgcn_mfma_f32_16x16x32_f16(af[mi], bf[ni], acc[mi][ni], 0, 0, 0);
        __builtin_amdgcn_s_setprio(0);
    };

    GSTAGE(0, 0); GSTAGE(1, 1);
#pragma unroll 1
    for (int ks = 0; ks < 14; ++ks) {
        asm volatile("s_waitcnt vmcnt(4)" ::: "memory");
        __builtin_amdgcn_s_barrier();
        __builtin_amdgcn_sched_barrier(0);
        GSTAGE((ks + 2) % 3, ks + 2);
        GTILE(ks);
    }
    asm volatile("s_waitcnt vmcnt(4)" ::: "memory");
    __builtin_amdgcn_s_barrier();
    GTILE(14);
    asm volatile("s_waitcnt vmcnt(0)" ::: "memory");
    __builtin_amdgcn_s_barrier();
    GTILE(15);

    // ---- epilogue: per-wave LDS stage (f16, pad-72 rows), coalesced stores ----
    __syncthreads();   // all waves done reading K-loop buffers
    _Float16* eb = (_Float16*)gsm + wid * 4608;   // 64 x 72 f16 = 9216 B per wave
    const int rr = lane >> 3, cc = lane & 7;

    if (mat < 2) {
        // row-major [ml][nl]
#pragma unroll
        for (int mi = 0; mi < 4; ++mi)
#pragma unroll
            for (int ni = 0; ni < 4; ++ni)
#pragma unroll
                for (int r = 0; r < 4; ++r)
                    eb[(mi * 16 + g * 4 + r) * 72 + ni * 16 + c] = (_Float16)acc[mi][ni][r];
        asm volatile("s_waitcnt lgkmcnt(0)" ::: "memory");
        _Float16* dstm = (mat == 0 ? qh : kh);
#pragma unroll
        for (int p = 0; p < 8; ++p) {
            int row = p * 8 + rr;
            f16x8 v = *(const f16x8*)&eb[row * 72 + cc * 8];
            *(f16x8*)(dstm + (size_t)(mtile * 128 + wm * 64 + row) * 512 +
                      ntile * 128 + wn * 64 + cc * 8) = v;
        }
    } else {
        // transposed [nl][ml] so vt rows ([d][s]) read back contiguously
#pragma unroll
        for (int mi = 0; mi < 4; ++mi)
#pragma unroll
            for (int ni = 0; ni < 4; ++ni)
#pragma unroll
                for (int r = 0; r < 4; ++r)
                    eb[(ni * 16 + c) * 72 + mi * 16 + g * 4 + r] = (_Float16)acc[mi][ni][r];
        asm volatile("s_waitcnt lgkmcnt(0)" ::: "memory");
        const int h = ntile * 2 + wn;                       // (ntile*128+wn*64)/64
        const int mbase = mtile * 128 + wm * 64;
        const int b = mbase >> 11, s0 = mbase & 2047;
#pragma unroll
        for (int p = 0; p < 8; ++p) {
            int d = p * 8 + rr;
            f16x8 v = *(const f16x8*)&eb[d * 72 + cc * 8];
            *(f16x8*)(vt + (((size_t)h * 4 + b) * 64 + d) * 2048 + s0 + cc * 8) = v;
        }
    }
}

// ---------------- kernel 3: flash attention + xcopy, 64-key tiles, staggered ---
__global__ __launch_bounds__(512, 4) void attn_kernel(
    const _Float16* __restrict__ qh, const _Float16* __restrict__ kh,
    const _Float16* __restrict__ vt, const float4* __restrict__ x4,
    float* __restrict__ out) {
    __shared__ __align__(16) char smem[65536];   // 2 sets x (K_A,V_A,K_B,V_B 8KB each)

    const int bid = blockIdx.x;
    const int xcd = bid & 7, idx = bid >> 3;     // idx 0..63
    const int hb = xcd * 4 + (idx >> 4);         // 0..31 (4 hb per XCD)
    const int qblk = idx & 15;                   // 0..15
    const int h = hb >> 2, b = hb & 3;
    const int tid = threadIdx.x, lane = tid & 63, wid = tid >> 6;  // wid 0..7
    const int qg = wid & 3, half = wid >> 2;
    const int q = lane & 31, hi = lane >> 5;

    // ---- xcopy slice: out[4M + bid*8192 .. +8192] = x (fp32 passthrough) ----
    {
        float4* xd = (float4*)(out + 4194304) + (size_t)bid * 2048;
        const float4* xs = x4 + (size_t)bid * 2048;
#pragma unroll
        for (int i = 0; i < 4; ++i) xd[i * 512 + tid] = xs[i * 512 + tid];
    }

    const int qrow0 = qblk * 128 + qg * 32;
    const _Float16* qp = qh + ((size_t)b * 2048 + qrow0) * 512 + h * 64;
    const _Float16* kp = kh + (size_t)b * 2048 * 512 + h * 64;
    const _Float16* vp = vt + (size_t)hb * 64 * 2048;

    const int srow = tid >> 3;
    const int ssw = (tid & 7) ^ ((srow ^ (srow >> 3)) & 7);

    auto STAGE = [&](int i) {
        char* base = smem + (i & 1) * 32768;
        GLD16(kp + ((size_t)(i * 64 + srow) * 512) + ssw * 8, (_Float16*)(base) + tid * 8);
        GLD16(vp + (size_t)srow * 2048 + i * 64 + ssw * 8, (_Float16*)(base + 8192) + tid * 8);
        GLD16(kp + ((size_t)((16 + i) * 64 + srow) * 512) + ssw * 8, (_Float16*)(base + 16384) + tid * 8);
        GLD16(vp + (size_t)srow * 2048 + (16 + i) * 64 + ssw * 8, (_Float16*)(base + 24576) + tid * 8);
    };

    f16x8 aQ[4];
#pragma unroll
    for (int kc = 0; kc < 4; ++kc)
        aQ[kc] = *(const f16x8*)(qp + (size_t)q * 512 + kc * 16 + hi * 8);

    float mrow = -1e30f, lrow = 0.f;   // lrow: LANE-PARTIAL
    f32x16 o0, o1;
#pragma unroll
    for (int i = 0; i < 16; ++i) { o0[i] = 0.f; o1[i] = 0.f; }

    const h16x2 ONE2 = {(__fp16)1.0f, (__fp16)1.0f};
    const int swr0 = (q ^ (q >> 3)) & 7;
    const int swr1 = ((32 + q) ^ ((32 + q) >> 3)) & 7;

    auto KPTR = [&](int t) {
        return (const _Float16*)(smem + (t & 1) * 32768 + half * 16384);
    };

    auto QKT2 = [&](const _Float16* kb, f32x16& s0, f32x16& s1) {
        f32x16 z0, z1;
#pragma unroll
        for (int i = 0; i < 16; ++i) { z0[i] = 0.f; z1[i] = 0.f; }
        __builtin_amdgcn_s_setprio(1);
#pragma unroll
        for (int kc = 0; kc < 4; ++kc) {
            f16x8 ak0 = *(const f16x8*)&kb[q * 64 + (((2 * kc + hi) ^ swr0) * 8)];
            f16x8 ak1 = *(const f16x8*)&kb[(32 + q) * 64 + (((2 * kc + hi) ^ swr1) * 8)];
            z0 = __builtin_amdgcn_mfma_f32_32x32x16_f16(ak0, aQ[kc], z0, 0, 0, 0);
            z1 = __builtin_amdgcn_mfma_f32_32x32x16_f16(ak1, aQ[kc], z1, 0, 0, 0);
        }
        __builtin_amdgcn_s_setprio(0);
        s0 = z0; s1 = z1;
    };

    auto SMPV2 = [&](f32x16& s0, f32x16& s1, const _Float16* vb) {
        float pm;
        {
            float m0 = fmaxf(fmaxf(fmaxf(s0[0], s0[1]), s0[2]), s0[3]);
            float m1 = fmaxf(fmaxf(fmaxf(s0[4], s0[5]), s0[6]), s0[7]);
            float m2 = fmaxf(fmaxf(fmaxf(s0[8], s0[9]), s0[10]), s0[11]);
            float m3 = fmaxf(fmaxf(fmaxf(s0[12], s0[13]), s0[14]), s0[15]);
            float m4 = fmaxf(fmaxf(fmaxf(s1[0], s1[1]), s1[2]), s1[3]);
            float m5 = fmaxf(fmaxf(fmaxf(s1[4], s1[5]), s1[6]), s1[7]);
            float m6 = fmaxf(fmaxf(fmaxf(s1[8], s1[9]), s1[10]), s1[11]);
            float m7 = fmaxf(fmaxf(fmaxf(s1[12], s1[13]), s1[14]), s1[15]);
            float t0 = fmaxf(fmaxf(m0, m1), m2);
            float t1 = fmaxf(fmaxf(m3, m4), m5);
            float t2 = fmaxf(m6, m7);
            pm = fmaxf(fmaxf(t0, t1), t2);
        }
        pm = fmaxf(pm, __shfl_xor(pm, 32));
        if (__any(pm > mrow + 8.0f)) {
            const float nm = fmaxf(mrow, pm);
            const float e = __builtin_amdgcn_exp2f((mrow - nm) * LOG2E);
            mrow = nm;
            lrow *= e;
            o0 *= e;
            o1 *= e;
        }
        const float nm2 = mrow * LOG2E;

#pragma unroll
        for (int i = 0; i < 16; ++i)
            s0[i] = __builtin_amdgcn_exp2f(fmaf(s0[i], LOG2E, -nm2));
#pragma unroll
        for (int i = 0; i < 16; ++i)
            s1[i] = __builtin_amdgcn_exp2f(fmaf(s1[i], LOG2E, -nm2));

        f16x8 pf[4];
        float rsA = 0.f, rsB = 0.f;
#pragma unroll
        for (int kb2 = 0; kb2 < 2; ++kb2) {
            const f32x16& sv = kb2 ? s1 : s0;
            h16x2 p0 = __builtin_amdgcn_cvt_pkrtz(sv[0], sv[1]);
            h16x2 p1 = __builtin_amdgcn_cvt_pkrtz(sv[2], sv[3]);
            h16x2 p2 = __builtin_amdgcn_cvt_pkrtz(sv[4], sv[5]);
            h16x2 p3 = __builtin_amdgcn_cvt_pkrtz(sv[6], sv[7]);
            h16x2 p4 = __builtin_amdgcn_cvt_pkrtz(sv[8], sv[9]);
            h16x2 p5 = __builtin_amdgcn_cvt_pkrtz(sv[10], sv[11]);
            h16x2 p6 = __builtin_amdgcn_cvt_pkrtz(sv[12], sv[13]);
            h16x2 p7 = __builtin_amdgcn_cvt_pkrtz(sv[14], sv[15]);
            rsA = __builtin_amdgcn_fdot2(p0, ONE2, rsA, false);
            rsB = __builtin_amdgcn_fdot2(p1, ONE2, rsB, false);
            rsA = __builtin_amdgcn_fdot2(p2, ONE2, rsA, false);
            rsB = __builtin_amdgcn_fdot2(p3, ONE2, rsB, false);
            rsA = __builtin_amdgcn_fdot2(p4, ONE2, rsA, false);
            rsB = __builtin_amdgcn_fdot2(p5, ONE2, rsB, false);
            rsA = __builtin_amdgcn_fdot2(p6, ONE2, rsA, false);
            rsB = __builtin_amdgcn_fdot2(p7, ONE2, rsB, false);
            unsigned t0 = __builtin_bit_cast(unsigned, p0);
            unsigned t1 = __builtin_bit_cast(unsigned, p1);
            unsigned t2 = __builtin_bit_cast(unsigned, p2);
            unsigned t3 = __builtin_bit_cast(unsigned, p3);
            unsigned t4 = __builtin_bit_cast(unsigned, p4);
            unsigned t5 = __builtin_bit_cast(unsigned, p5);
            unsigned t6 = __builtin_bit_cast(unsigned, p6);
            unsigned t7 = __builtin_bit_cast(unsigned, p7);
            asm volatile("v_permlane32_swap_b32 %0, %1" : "+v"(t0), "+v"(t2));
            asm volatile("v_permlane32_swap_b32 %0, %1" : "+v"(t1), "+v"(t3));
            asm volatile("v_permlane32_swap_b32 %0, %1" : "+v"(t4), "+v"(t6));
            asm volatile("v_permlane32_swap_b32 %0, %1" : "+v"(t5), "+v"(t7));
            uint4 u0; u0.x = t0; u0.y = t1; u0.z = t2; u0.w = t3;
            uint4 u1; u1.x = t4; u1.y = t5; u1.z = t6; u1.w = t7;
            pf[2 * kb2 + 0] = __builtin_bit_cast(f16x8, u0);
            pf[2 * kb2 + 1] = __builtin_bit_cast(f16x8, u1);
        }
        lrow += rsA + rsB;

        __builtin_amdgcn_s_setprio(1);
#pragma unroll
        for (int ck = 0; ck < 4; ++ck) {
            f16x8 av0 = *(const f16x8*)&vb[q * 64 + (((2 * ck + hi) ^ swr0) * 8)];
            f16x8 av1 = *(const f16x8*)&vb[(32 + q) * 64 + (((2 * ck + hi) ^ swr1) * 8)];
            o0 = __builtin_amdgcn_mfma_f32_32x32x16_f16(av0, pf[ck], o0, 0, 0, 0);
            o1 = __builtin_amdgcn_mfma_f32_32x32x16_f16(av1, pf[ck], o1, 0, 0, 0);
        }
        __builtin_amdgcn_s_setprio(0);
    };

#define WAITBAR() do { \
    asm volatile("s_waitcnt vmcnt(0)" ::: "memory"); \
    __builtin_amdgcn_s_barrier(); \
    __builtin_amdgcn_sched_barrier(0); \
} while (0)

    f32x16 s0, s1;
    STAGE(0);
    if (half == 0) {
#pragma unroll 1
        for (int t = 0; t < 16; ++t) {
            WAITBAR();
            if (t < 15) STAGE(t + 1);
            QKT2(KPTR(t), s0, s1);
            SMPV2(s0, s1, KPTR(t) + 4096);
        }
    } else {
        WAITBAR();
        STAGE(1);
        QKT2(KPTR(0), s0, s1);
#pragma unroll 1
        for (int t = 1; t < 16; ++t) {
            SMPV2(s0, s1, KPTR(t - 1) + 4096);
            WAITBAR();
            if (t < 15) STAGE(t + 1);
            QKT2(KPTR(t), s0, s1);
        }
        SMPV2(s0, s1, KPTR(15) + 4096);
    }

    // ---- flash-decode merge: half B hands (o, m, l) to half A via LDS ----
    lrow += __shfl_xor(lrow, 32);
    __builtin_amdgcn_s_barrier();

    float* xg = (float*)smem + qg * 2112;
    if (half) {
#pragma unroll
        for (int i = 0; i < 16; ++i) {
            xg[i * 64 + lane] = o0[i];
            xg[(16 + i) * 64 + lane] = o1[i];
        }
        if (!hi) { xg[2048 + q] = mrow; xg[2080 + q] = lrow; }
    }
    __syncthreads();
    if (!half) {
        const float m_b = xg[2048 + q], l_b = xg[2080 + q];
        const float m = fmaxf(mrow, m_b);
        const float e_a = __builtin_amdgcn_exp2f((mrow - m) * LOG2E);
        const float e_b = __builtin_amdgcn_exp2f((m_b - m) * LOG2E);
        const float inv = 1.0f / (lrow * e_a + l_b * e_b);
        const float sa = e_a * inv, sb = e_b * inv;
#pragma unroll
        for (int i = 0; i < 16; ++i) {
            o0[i] = o0[i] * sa + xg[i * 64 + lane] * sb;
            o1[i] = o1[i] * sa + xg[(16 + i) * 64 + lane] * sb;
        }
        asm volatile("s_waitcnt lgkmcnt(0)" ::: "memory");
#pragma unroll
        for (int i = 0; i < 16; ++i) {
            int dr = (i & 3) + 8 * (i >> 2) + 4 * hi;
            xg[dr * 33 + q] = o0[i];
            xg[(32 + dr) * 33 + q] = o1[i];
        }
        __builtin_amdgcn_s_waitcnt(0);
        const int d0c = (lane & 15) * 4;
#pragma unroll
        for (int i2 = 0; i2 < 8; ++i2) {
            int qr = 4 * i2 + (lane >> 4);
            float4 v;
            v.x = xg[(d0c + 0) * 33 + qr];
            v.y = xg[(d0c + 1) * 33 + qr];
            v.z = xg[(d0c + 2) * 33 + qr];
            v.w = xg[(d0c + 3) * 33 + qr];
            *(float4*)(out + ((size_t)b * 2048 + qrow0 + qr) * 512 + h * 64 + d0c) = v;
        }
    }
#undef WAITBAR
}

extern "C" void kernel_launch(void* const* d_in, const int* in_sizes, int n_in,
                              void* d_out, int out_size, void* d_ws, size_t ws_size,
                              hipStream_t stream) {
    const float* x = (const float*)d_in[0];
    const float* Wq = (const float*)d_in[1];
    const float* Wk = (const float*)d_in[2];
    const float* Wv = (const float*)d_in[3];
    float* out = (float*)d_out;

    char* ws = (char*)d_ws;
    _Float16* xh = (_Float16*)ws;                          // 8 MB
    _Float16* wt = (_Float16*)(ws + (size_t)(10u << 20));  // 1.5 MB
    _Float16* qh = (_Float16*)(ws + (size_t)(12u << 20));  // 8 MB
    _Float16* kh = (_Float16*)(ws + (size_t)(20u << 20));  // 8 MB
    _Float16* vt = (_Float16*)(ws + (size_t)(28u << 20));  // 8 MB

    cvt_all_kernel<<<5120, 256, 0, stream>>>((const float4*)x, (f16x8*)xh,
                                             Wq, Wk, Wv, wt);
    gemm_qkv<<<dim3(256, 3), 256, 0, stream>>>(xh, wt, qh, kh, vt);
    attn_kernel<<<512, 512, 0, stream>>>(qh, kh, vt, (const float4*)x, out);
}

// Round 15
// 84.514 us; speedup vs baseline: 1.1203x; 1.0359x over previous
//
#include <hip/hip_runtime.h>

typedef _Float16 f16x8 __attribute__((ext_vector_type(8)));
typedef __fp16 h16x2 __attribute__((ext_vector_type(2)));
typedef float f32x4 __attribute__((ext_vector_type(4)));
typedef float f32x16 __attribute__((ext_vector_type(16)));

#define GF(r) ((((r)&3)) ^ (((r)>>2)&3))
#define LOG2E 1.44269504088896f

#define GLD16(gp, lp) __builtin_amdgcn_global_load_lds( \
    (const __attribute__((address_space(1))) void*)(gp), \
    (__attribute__((address_space(3))) void*)(lp), 16, 0, 0)

// ---- kernel 1: x -> fp16 (blocks 0..2047); W -> W^T fp16 via LDS transpose ----
__global__ void cvt_all_kernel(const float4* __restrict__ x4, f16x8* __restrict__ xh,
                               const float* __restrict__ Wq, const float* __restrict__ Wk,
                               const float* __restrict__ Wv, _Float16* __restrict__ wt) {
    const int blk = blockIdx.x;
    const int tid = threadIdx.x;
    if (blk < 2048) {
        int i = blk * 256 + tid;
        float4 a = x4[2 * i], b = x4[2 * i + 1];
        f16x8 h;
        h[0] = (_Float16)a.x; h[1] = (_Float16)a.y; h[2] = (_Float16)a.z; h[3] = (_Float16)a.w;
        h[4] = (_Float16)b.x; h[5] = (_Float16)b.y; h[6] = (_Float16)b.z; h[7] = (_Float16)b.w;
        xh[i] = h;
    } else {
        // W transpose: 192 blocks = 3 mats x 64 tiles (8x8 of 64x64)
        __shared__ _Float16 lt[64 * 66];
        const int t = blk - 2048;
        const int mat = t >> 6, tile = t & 63;
        const int r0 = (tile >> 3) * 64, n0 = (tile & 7) * 64;
        const float* W = (mat == 0) ? Wq : ((mat == 1) ? Wk : Wv);
        const int rr = tid >> 4, c4 = tid & 15;
#pragma unroll
        for (int i = 0; i < 4; ++i) {
            int row = rr + i * 16;
            float4 v = *(const float4*)&W[(size_t)(r0 + row) * 512 + n0 + c4 * 4];
            lt[(c4 * 4 + 0) * 66 + row] = (_Float16)v.x;
            lt[(c4 * 4 + 1) * 66 + row] = (_Float16)v.y;
            lt[(c4 * 4 + 2) * 66 + row] = (_Float16)v.z;
            lt[(c4 * 4 + 3) * 66 + row] = (_Float16)v.w;
        }
        __syncthreads();
        const int nl = tid >> 2, rc = tid & 3;
        _Float16* dst = wt + (size_t)mat * 262144 + (size_t)(n0 + nl) * 512 + r0 + rc * 16;
#pragma unroll
        for (int u = 0; u < 2; ++u)
            *(f16x8*)(dst + u * 8) = *(const f16x8*)&lt[nl * 66 + rc * 16 + u * 8];
    }
}

// ---------------- kernel 2: QKV GEMM (fp16 MFMA, 3-buf counted-vmcnt) ----------
// 3 blocks/CU (768 blocks = exactly one full round on 256 CUs).
__global__ __launch_bounds__(256, 3) void gemm_qkv(
    const _Float16* __restrict__ xh, const _Float16* __restrict__ wt,
    _Float16* __restrict__ qh, _Float16* __restrict__ kh, _Float16* __restrict__ vt) {
    __shared__ __align__(16) char gsm[49152];   // 3 bufs x (8KB A + 8KB B); epi reuse
    const int mat = blockIdx.y;
    const _Float16* wp = wt + (size_t)mat * 262144;
    const int mtile = blockIdx.x >> 2, ntile = blockIdx.x & 3;
    const int tid = threadIdx.x, lane = tid & 63;
    const int g = lane >> 4, c = lane & 15;
    const int wid = tid >> 6, wm = wid >> 1, wn = wid & 1;

    f32x4 acc[4][4];
#pragma unroll
    for (int i = 0; i < 4; ++i)
#pragma unroll
        for (int j = 0; j < 4; ++j) acc[i][j] = (f32x4){0.f, 0.f, 0.f, 0.f};

    const int row0 = tid >> 2, p0 = tid & 3;

    auto GSTAGE = [&](int buf, int ks) {
        _Float16* la_ = (_Float16*)(gsm + buf * 16384);
        _Float16* lb_ = (_Float16*)(gsm + buf * 16384 + 8192);
        int r = row0, pp = p0 ^ GF(r);
        GLD16(xh + (size_t)(mtile * 128 + r) * 512 + ks * 32 + pp * 8, &la_[tid * 8]);
        GLD16(wp + (size_t)(ntile * 128 + r) * 512 + ks * 32 + pp * 8, &lb_[tid * 8]);
        r = 64 + row0; pp = p0 ^ GF(r);
        GLD16(xh + (size_t)(mtile * 128 + r) * 512 + ks * 32 + pp * 8, &la_[(256 + tid) * 8]);
        GLD16(wp + (size_t)(ntile * 128 + r) * 512 + ks * 32 + pp * 8, &lb_[(256 + tid) * 8]);
    };

    auto GTILE = [&](int ks) {
        const _Float16* la = (const _Float16*)(gsm + (ks % 3) * 16384);
        const _Float16* lb = (const _Float16*)(gsm + (ks % 3) * 16384 + 8192);
        f16x8 af[4], bf[4];
#pragma unroll
        for (int i = 0; i < 4; ++i) {
            int ra = wm * 64 + i * 16 + c;
            af[i] = *(const f16x8*)&la[ra * 32 + ((g ^ GF(ra)) * 8)];
            int rb = wn * 64 + i * 16 + c;
            bf[i] = *(const f16x8*)&lb[rb * 32 + ((g ^ GF(rb)) * 8)];
        }
        __builtin_amdgcn_s_setprio(1);
#pragma unroll
        for (int mi = 0; mi < 4; ++mi)
#pragma unroll
            for (int ni = 0; ni < 4; ++ni)
                acc[mi][ni] = __builtin_amdgcn_mfma_f32_16x16x32_f16(af[mi], bf[ni], acc[mi][ni], 0, 0, 0);
        __builtin_amdgcn_s_setprio(0);
    };

    GSTAGE(0, 0); GSTAGE(1, 1);
#pragma unroll 1
    for (int ks = 0; ks < 14; ++ks) {
        asm volatile("s_waitcnt vmcnt(4)" ::: "memory");
        __builtin_amdgcn_s_barrier();
        __builtin_amdgcn_sched_barrier(0);
        GSTAGE((ks + 2) % 3, ks + 2);
        GTILE(ks);
    }
    asm volatile("s_waitcnt vmcnt(4)" ::: "memory");
    __builtin_amdgcn_s_barrier();
    GTILE(14);
    asm volatile("s_waitcnt vmcnt(0)" ::: "memory");
    __builtin_amdgcn_s_barrier();
    GTILE(15);

    // ---- epilogue: per-wave LDS stage (f16, pad-72 rows), coalesced stores ----
    __syncthreads();
    _Float16* eb = (_Float16*)gsm + wid * 4608;   // 64 x 72 f16 = 9216 B per wave
    const int rr = lane >> 3, cc = lane & 7;

    if (mat < 2) {
#pragma unroll
        for (int mi = 0; mi < 4; ++mi)
#pragma unroll
            for (int ni = 0; ni < 4; ++ni)
#pragma unroll
                for (int r = 0; r < 4; ++r)
                    eb[(mi * 16 + g * 4 + r) * 72 + ni * 16 + c] = (_Float16)acc[mi][ni][r];
        asm volatile("s_waitcnt lgkmcnt(0)" ::: "memory");
        _Float16* dstm = (mat == 0 ? qh : kh);
#pragma unroll
        for (int p = 0; p < 8; ++p) {
            int row = p * 8 + rr;
            f16x8 v = *(const f16x8*)&eb[row * 72 + cc * 8];
            *(f16x8*)(dstm + (size_t)(mtile * 128 + wm * 64 + row) * 512 +
                      ntile * 128 + wn * 64 + cc * 8) = v;
        }
    } else {
#pragma unroll
        for (int mi = 0; mi < 4; ++mi)
#pragma unroll
            for (int ni = 0; ni < 4; ++ni)
#pragma unroll
                for (int r = 0; r < 4; ++r)
                    eb[(ni * 16 + c) * 72 + mi * 16 + g * 4 + r] = (_Float16)acc[mi][ni][r];
        asm volatile("s_waitcnt lgkmcnt(0)" ::: "memory");
        const int h = ntile * 2 + wn;
        const int mbase = mtile * 128 + wm * 64;
        const int b = mbase >> 11, s0 = mbase & 2047;
#pragma unroll
        for (int p = 0; p < 8; ++p) {
            int d = p * 8 + rr;
            f16x8 v = *(const f16x8*)&eb[d * 72 + cc * 8];
            *(f16x8*)(vt + (((size_t)h * 4 + b) * 64 + d) * 2048 + s0 + cc * 8) = v;
        }
    }
}

// ---------------- kernel 3: flash attention + xcopy, 64-key tiles, staggered ---
__global__ __launch_bounds__(512, 4) void attn_kernel(
    const _Float16* __restrict__ qh, const _Float16* __restrict__ kh,
    const _Float16* __restrict__ vt, const float4* __restrict__ x4,
    float* __restrict__ out) {
    __shared__ __align__(16) char smem[65536];   // 2 sets x (K_A,V_A,K_B,V_B 8KB each)

    const int bid = blockIdx.x;
    const int xcd = bid & 7, idx = bid >> 3;
    const int hb = xcd * 4 + (idx >> 4);
    const int qblk = idx & 15;
    const int h = hb >> 2, b = hb & 3;
    const int tid = threadIdx.x, lane = tid & 63, wid = tid >> 6;
    const int qg = wid & 3, half = wid >> 2;
    const int q = lane & 31, hi = lane >> 5;

    // ---- xcopy slice ----
    {
        float4* xd = (float4*)(out + 4194304) + (size_t)bid * 2048;
        const float4* xs = x4 + (size_t)bid * 2048;
#pragma unroll
        for (int i = 0; i < 4; ++i) xd[i * 512 + tid] = xs[i * 512 + tid];
    }

    const int qrow0 = qblk * 128 + qg * 32;
    const _Float16* qp = qh + ((size_t)b * 2048 + qrow0) * 512 + h * 64;
    const _Float16* kp = kh + (size_t)b * 2048 * 512 + h * 64;
    const _Float16* vp = vt + (size_t)hb * 64 * 2048;

    const int srow = tid >> 3;
    const int ssw = (tid & 7) ^ ((srow ^ (srow >> 3)) & 7);

    auto STAGE = [&](int i) {
        char* base = smem + (i & 1) * 32768;
        GLD16(kp + ((size_t)(i * 64 + srow) * 512) + ssw * 8, (_Float16*)(base) + tid * 8);
        GLD16(vp + (size_t)srow * 2048 + i * 64 + ssw * 8, (_Float16*)(base + 8192) + tid * 8);
        GLD16(kp + ((size_t)((16 + i) * 64 + srow) * 512) + ssw * 8, (_Float16*)(base + 16384) + tid * 8);
        GLD16(vp + (size_t)srow * 2048 + (16 + i) * 64 + ssw * 8, (_Float16*)(base + 24576) + tid * 8);
    };

    f16x8 aQ[4];
#pragma unroll
    for (int kc = 0; kc < 4; ++kc)
        aQ[kc] = *(const f16x8*)(qp + (size_t)q * 512 + kc * 16 + hi * 8);

    float mrow = -1e30f, lrow = 0.f;
    f32x16 o0, o1;
#pragma unroll
    for (int i = 0; i < 16; ++i) { o0[i] = 0.f; o1[i] = 0.f; }

    const h16x2 ONE2 = {(__fp16)1.0f, (__fp16)1.0f};
    const int swr0 = (q ^ (q >> 3)) & 7;
    const int swr1 = ((32 + q) ^ ((32 + q) >> 3)) & 7;

    auto KPTR = [&](int t) {
        return (const _Float16*)(smem + (t & 1) * 32768 + half * 16384);
    };

    auto QKT2 = [&](const _Float16* kb, f32x16& s0, f32x16& s1) {
        f32x16 z0, z1;
#pragma unroll
        for (int i = 0; i < 16; ++i) { z0[i] = 0.f; z1[i] = 0.f; }
        __builtin_amdgcn_s_setprio(1);
#pragma unroll
        for (int kc = 0; kc < 4; ++kc) {
            f16x8 ak0 = *(const f16x8*)&kb[q * 64 + (((2 * kc + hi) ^ swr0) * 8)];
            f16x8 ak1 = *(const f16x8*)&kb[(32 + q) * 64 + (((2 * kc + hi) ^ swr1) * 8)];
            z0 = __builtin_amdgcn_mfma_f32_32x32x16_f16(ak0, aQ[kc], z0, 0, 0, 0);
            z1 = __builtin_amdgcn_mfma_f32_32x32x16_f16(ak1, aQ[kc], z1, 0, 0, 0);
        }
        __builtin_amdgcn_s_setprio(0);
        s0 = z0; s1 = z1;
    };

    auto SMPV2 = [&](f32x16& s0, f32x16& s1, const _Float16* vb) {
        float pm;
        {
            float m0 = fmaxf(fmaxf(fmaxf(s0[0], s0[1]), s0[2]), s0[3]);
            float m1 = fmaxf(fmaxf(fmaxf(s0[4], s0[5]), s0[6]), s0[7]);
            float m2 = fmaxf(fmaxf(fmaxf(s0[8], s0[9]), s0[10]), s0[11]);
            float m3 = fmaxf(fmaxf(fmaxf(s0[12], s0[13]), s0[14]), s0[15]);
            float m4 = fmaxf(fmaxf(fmaxf(s1[0], s1[1]), s1[2]), s1[3]);
            float m5 = fmaxf(fmaxf(fmaxf(s1[4], s1[5]), s1[6]), s1[7]);
            float m6 = fmaxf(fmaxf(fmaxf(s1[8], s1[9]), s1[10]), s1[11]);
            float m7 = fmaxf(fmaxf(fmaxf(s1[12], s1[13]), s1[14]), s1[15]);
            float t0 = fmaxf(fmaxf(m0, m1), m2);
            float t1 = fmaxf(fmaxf(m3, m4), m5);
            float t2 = fmaxf(m6, m7);
            pm = fmaxf(fmaxf(t0, t1), t2);
        }
        pm = fmaxf(pm, __shfl_xor(pm, 32));
        if (__any(pm > mrow + 8.0f)) {
            const float nm = fmaxf(mrow, pm);
            const float e = __builtin_amdgcn_exp2f((mrow - nm) * LOG2E);
            mrow = nm;
            lrow *= e;
            o0 *= e;
            o1 *= e;
        }
        const float nm2 = mrow * LOG2E;

#pragma unroll
        for (int i = 0; i < 16; ++i)
            s0[i] = __builtin_amdgcn_exp2f(fmaf(s0[i], LOG2E, -nm2));
#pragma unroll
        for (int i = 0; i < 16; ++i)
            s1[i] = __builtin_amdgcn_exp2f(fmaf(s1[i], LOG2E, -nm2));

        f16x8 pf[4];
        float rsA = 0.f, rsB = 0.f;
#pragma unroll
        for (int kb2 = 0; kb2 < 2; ++kb2) {
            const f32x16& sv = kb2 ? s1 : s0;
            h16x2 p0 = __builtin_amdgcn_cvt_pkrtz(sv[0], sv[1]);
            h16x2 p1 = __builtin_amdgcn_cvt_pkrtz(sv[2], sv[3]);
            h16x2 p2 = __builtin_amdgcn_cvt_pkrtz(sv[4], sv[5]);
            h16x2 p3 = __builtin_amdgcn_cvt_pkrtz(sv[6], sv[7]);
            h16x2 p4 = __builtin_amdgcn_cvt_pkrtz(sv[8], sv[9]);
            h16x2 p5 = __builtin_amdgcn_cvt_pkrtz(sv[10], sv[11]);
            h16x2 p6 = __builtin_amdgcn_cvt_pkrtz(sv[12], sv[13]);
            h16x2 p7 = __builtin_amdgcn_cvt_pkrtz(sv[14], sv[15]);
            rsA = __builtin_amdgcn_fdot2(p0, ONE2, rsA, false);
            rsB = __builtin_amdgcn_fdot2(p1, ONE2, rsB, false);
            rsA = __builtin_amdgcn_fdot2(p2, ONE2, rsA, false);
            rsB = __builtin_amdgcn_fdot2(p3, ONE2, rsB, false);
            rsA = __builtin_amdgcn_fdot2(p4, ONE2, rsA, false);
            rsB = __builtin_amdgcn_fdot2(p5, ONE2, rsB, false);
            rsA = __builtin_amdgcn_fdot2(p6, ONE2, rsA, false);
            rsB = __builtin_amdgcn_fdot2(p7, ONE2, rsB, false);
            unsigned t0 = __builtin_bit_cast(unsigned, p0);
            unsigned t1 = __builtin_bit_cast(unsigned, p1);
            unsigned t2 = __builtin_bit_cast(unsigned, p2);
            unsigned t3 = __builtin_bit_cast(unsigned, p3);
            unsigned t4 = __builtin_bit_cast(unsigned, p4);
            unsigned t5 = __builtin_bit_cast(unsigned, p5);
            unsigned t6 = __builtin_bit_cast(unsigned, p6);
            unsigned t7 = __builtin_bit_cast(unsigned, p7);
            asm volatile("v_permlane32_swap_b32 %0, %1" : "+v"(t0), "+v"(t2));
            asm volatile("v_permlane32_swap_b32 %0, %1" : "+v"(t1), "+v"(t3));
            asm volatile("v_permlane32_swap_b32 %0, %1" : "+v"(t4), "+v"(t6));
            asm volatile("v_permlane32_swap_b32 %0, %1" : "+v"(t5), "+v"(t7));
            uint4 u0; u0.x = t0; u0.y = t1; u0.z = t2; u0.w = t3;
            uint4 u1; u1.x = t4; u1.y = t5; u1.z = t6; u1.w = t7;
            pf[2 * kb2 + 0] = __builtin_bit_cast(f16x8, u0);
            pf[2 * kb2 + 1] = __builtin_bit_cast(f16x8, u1);
        }
        lrow += rsA + rsB;

        __builtin_amdgcn_s_setprio(1);
#pragma unroll
        for (int ck = 0; ck < 4; ++ck) {
            f16x8 av0 = *(const f16x8*)&vb[q * 64 + (((2 * ck + hi) ^ swr0) * 8)];
            f16x8 av1 = *(const f16x8*)&vb[(32 + q) * 64 + (((2 * ck + hi) ^ swr1) * 8)];
            o0 = __builtin_amdgcn_mfma_f32_32x32x16_f16(av0, pf[ck], o0, 0, 0, 0);
            o1 = __builtin_amdgcn_mfma_f32_32x32x16_f16(av1, pf[ck], o1, 0, 0, 0);
        }
        __builtin_amdgcn_s_setprio(0);
    };

#define WAITBAR() do { \
    asm volatile("s_waitcnt vmcnt(0)" ::: "memory"); \
    __builtin_amdgcn_s_barrier(); \
    __builtin_amdgcn_sched_barrier(0); \
} while (0)

    f32x16 s0, s1;
    STAGE(0);
    if (half == 0) {
#pragma unroll 1
        for (int t = 0; t < 16; ++t) {
            WAITBAR();
            if (t < 15) STAGE(t + 1);
            QKT2(KPTR(t), s0, s1);
            SMPV2(s0, s1, KPTR(t) + 4096);
        }
    } else {
        WAITBAR();
        STAGE(1);
        QKT2(KPTR(0), s0, s1);
#pragma unroll 1
        for (int t = 1; t < 16; ++t) {
            SMPV2(s0, s1, KPTR(t - 1) + 4096);
            WAITBAR();
            if (t < 15) STAGE(t + 1);
            QKT2(KPTR(t), s0, s1);
        }
        SMPV2(s0, s1, KPTR(15) + 4096);
    }

    // ---- flash-decode merge: half B hands (o, m, l) to half A via LDS ----
    lrow += __shfl_xor(lrow, 32);
    __builtin_amdgcn_s_barrier();

    float* xg = (float*)smem + qg * 2112;
    if (half) {
#pragma unroll
        for (int i = 0; i < 16; ++i) {
            xg[i * 64 + lane] = o0[i];
            xg[(16 + i) * 64 + lane] = o1[i];
        }
        if (!hi) { xg[2048 + q] = mrow; xg[2080 + q] = lrow; }
    }
    __syncthreads();
    if (!half) {
        const float m_b = xg[2048 + q], l_b = xg[2080 + q];
        const float m = fmaxf(mrow, m_b);
        const float e_a = __builtin_amdgcn_exp2f((mrow - m) * LOG2E);
        const float e_b = __builtin_amdgcn_exp2f((m_b - m) * LOG2E);
        const float inv = 1.0f / (lrow * e_a + l_b * e_b);
        const float sa = e_a * inv, sb = e_b * inv;
#pragma unroll
        for (int i = 0; i < 16; ++i) {
            o0[i] = o0[i] * sa + xg[i * 64 + lane] * sb;
            o1[i] = o1[i] * sa + xg[(16 + i) * 64 + lane] * sb;
        }
        asm volatile("s_waitcnt lgkmcnt(0)" ::: "memory");
#pragma unroll
        for (int i = 0; i < 16; ++i) {
            int dr = (i & 3) + 8 * (i >> 2) + 4 * hi;
            xg[dr * 33 + q] = o0[i];
            xg[(32 + dr) * 33 + q] = o1[i];
        }
        __builtin_amdgcn_s_waitcnt(0);
        const int d0c = (lane & 15) * 4;
#pragma unroll
        for (int i2 = 0; i2 < 8; ++i2) {
            int qr = 4 * i2 + (lane >> 4);
            float4 v;
            v.x = xg[(d0c + 0) * 33 + qr];
            v.y = xg[(d0c + 1) * 33 + qr];
            v.z = xg[(d0c + 2) * 33 + qr];
            v.w = xg[(d0c + 3) * 33 + qr];
            *(float4*)(out + ((size_t)b * 2048 + qrow0 + qr) * 512 + h * 64 + d0c) = v;
        }
    }
#undef WAITBAR
}

extern "C" void kernel_launch(void* const* d_in, const int* in_sizes, int n_in,
                              void* d_out, int out_size, void* d_ws, size_t ws_size,
                              hipStream_t stream) {
    const float* x = (const float*)d_in[0];
    const float* Wq = (const float*)d_in[1];
    const float* Wk = (const float*)d_in[2];
    const float* Wv = (const float*)d_in[3];
    float* out = (float*)d_out;

    char* ws = (char*)d_ws;
    _Float16* xh = (_Float16*)ws;                          // 8 MB
    _Float16* wt = (_Float16*)(ws + (size_t)(10u << 20));  // 1.5 MB
    _Float16* qh = (_Float16*)(ws + (size_t)(12u << 20));  // 8 MB
    _Float16* kh = (_Float16*)(ws + (size_t)(20u << 20));  // 8 MB
    _Float16* vt = (_Float16*)(ws + (size_t)(28u << 20));  // 8 MB

    cvt_all_kernel<<<2240, 256, 0, stream>>>((const float4*)x, (f16x8*)xh,
                                             Wq, Wk, Wv, wt);
    gemm_qkv<<<dim3(256, 3), 256, 0, stream>>>(xh, wt, qh, kh, vt);
    attn_kernel<<<512, 512, 0, stream>>>(qh, kh, vt, (const float4*)x, out);
}

// Round 16
// 84.358 us; speedup vs baseline: 1.1223x; 1.0018x over previous
//
#include <hip/hip_runtime.h>

typedef _Float16 f16x8 __attribute__((ext_vector_type(8)));
typedef __fp16 h16x2 __attribute__((ext_vector_type(2)));
typedef float f32x4 __attribute__((ext_vector_type(4)));
typedef float f32x16 __attribute__((ext_vector_type(16)));

#define GF(r) ((((r)&3)) ^ (((r)>>2)&3))
#define LOG2E 1.44269504088896f

#define GLD16(gp, lp) __builtin_amdgcn_global_load_lds( \
    (const __attribute__((address_space(1))) void*)(gp), \
    (__attribute__((address_space(3))) void*)(lp), 16, 0, 0)

// ---- kernel 1: x -> fp16 (blocks 0..2047); W -> W^T fp16 via LDS transpose ----
__global__ void cvt_all_kernel(const float4* __restrict__ x4, f16x8* __restrict__ xh,
                               const float* __restrict__ Wq, const float* __restrict__ Wk,
                               const float* __restrict__ Wv, _Float16* __restrict__ wt) {
    const int blk = blockIdx.x;
    const int tid = threadIdx.x;
    if (blk < 2048) {
        int i = blk * 256 + tid;
        float4 a = x4[2 * i], b = x4[2 * i + 1];
        f16x8 h;
        h[0] = (_Float16)a.x; h[1] = (_Float16)a.y; h[2] = (_Float16)a.z; h[3] = (_Float16)a.w;
        h[4] = (_Float16)b.x; h[5] = (_Float16)b.y; h[6] = (_Float16)b.z; h[7] = (_Float16)b.w;
        xh[i] = h;
    } else {
        // W transpose: 192 blocks = 3 mats x 64 tiles (8x8 of 64x64)
        __shared__ _Float16 lt[64 * 66];
        const int t = blk - 2048;
        const int mat = t >> 6, tile = t & 63;
        const int r0 = (tile >> 3) * 64, n0 = (tile & 7) * 64;
        const float* W = (mat == 0) ? Wq : ((mat == 1) ? Wk : Wv);
        const int rr = tid >> 4, c4 = tid & 15;
#pragma unroll
        for (int i = 0; i < 4; ++i) {
            int row = rr + i * 16;
            float4 v = *(const float4*)&W[(size_t)(r0 + row) * 512 + n0 + c4 * 4];
            lt[(c4 * 4 + 0) * 66 + row] = (_Float16)v.x;
            lt[(c4 * 4 + 1) * 66 + row] = (_Float16)v.y;
            lt[(c4 * 4 + 2) * 66 + row] = (_Float16)v.z;
            lt[(c4 * 4 + 3) * 66 + row] = (_Float16)v.w;
        }
        __syncthreads();
        const int nl = tid >> 2, rc = tid & 3;
        _Float16* dst = wt + (size_t)mat * 262144 + (size_t)(n0 + nl) * 512 + r0 + rc * 16;
#pragma unroll
        for (int u = 0; u < 2; ++u)
            *(f16x8*)(dst + u * 8) = *(const f16x8*)&lt[nl * 66 + rc * 16 + u * 8];
    }
}

// ---------------- kernel 2: QKV GEMM (fp16 MFMA, 3-buf counted-vmcnt) ----------
// Grid 768 flat; XCD-aware decode: all 12 blocks (3 mats x 4 ntiles) sharing an
// A-panel land on ONE XCD -> A-panel fetched from HBM once per XCD (L2-shared).
__global__ __launch_bounds__(256, 3) void gemm_qkv(
    const _Float16* __restrict__ xh, const _Float16* __restrict__ wt,
    _Float16* __restrict__ qh, _Float16* __restrict__ kh, _Float16* __restrict__ vt) {
    __shared__ __align__(16) char gsm[49152];   // 3 bufs x (8KB A + 8KB B); epi reuse
    const int bid = blockIdx.x;
    const int xcdid = bid & 7, slot = bid >> 3;      // 96 slots per XCD
    const int mtile = xcdid * 8 + (slot / 12);
    const int rem = slot % 12;
    const int mat = rem >> 2, ntile = rem & 3;
    const _Float16* wp = wt + (size_t)mat * 262144;
    const int tid = threadIdx.x, lane = tid & 63;
    const int g = lane >> 4, c = lane & 15;
    const int wid = tid >> 6, wm = wid >> 1, wn = wid & 1;

    f32x4 acc[4][4];
#pragma unroll
    for (int i = 0; i < 4; ++i)
#pragma unroll
        for (int j = 0; j < 4; ++j) acc[i][j] = (f32x4){0.f, 0.f, 0.f, 0.f};

    const int row0 = tid >> 2, p0 = tid & 3;

    auto GSTAGE = [&](int buf, int ks) {
        _Float16* la_ = (_Float16*)(gsm + buf * 16384);
        _Float16* lb_ = (_Float16*)(gsm + buf * 16384 + 8192);
        int r = row0, pp = p0 ^ GF(r);
        GLD16(xh + (size_t)(mtile * 128 + r) * 512 + ks * 32 + pp * 8, &la_[tid * 8]);
        GLD16(wp + (size_t)(ntile * 128 + r) * 512 + ks * 32 + pp * 8, &lb_[tid * 8]);
        r = 64 + row0; pp = p0 ^ GF(r);
        GLD16(xh + (size_t)(mtile * 128 + r) * 512 + ks * 32 + pp * 8, &la_[(256 + tid) * 8]);
        GLD16(wp + (size_t)(ntile * 128 + r) * 512 + ks * 32 + pp * 8, &lb_[(256 + tid) * 8]);
    };

    auto GTILE = [&](int ks) {
        const _Float16* la = (const _Float16*)(gsm + (ks % 3) * 16384);
        const _Float16* lb = (const _Float16*)(gsm + (ks % 3) * 16384 + 8192);
        f16x8 af[4], bf[4];
#pragma unroll
        for (int i = 0; i < 4; ++i) {
            int ra = wm * 64 + i * 16 + c;
            af[i] = *(const f16x8*)&la[ra * 32 + ((g ^ GF(ra)) * 8)];
            int rb = wn * 64 + i * 16 + c;
            bf[i] = *(const f16x8*)&lb[rb * 32 + ((g ^ GF(rb)) * 8)];
        }
        __builtin_amdgcn_s_setprio(1);
#pragma unroll
        for (int mi = 0; mi < 4; ++mi)
#pragma unroll
            for (int ni = 0; ni < 4; ++ni)
                acc[mi][ni] = __builtin_amdgcn_mfma_f32_16x16x32_f16(af[mi], bf[ni], acc[mi][ni], 0, 0, 0);
        __builtin_amdgcn_s_setprio(0);
    };

    GSTAGE(0, 0); GSTAGE(1, 1);
#pragma unroll 1
    for (int ks = 0; ks < 14; ++ks) {
        asm volatile("s_waitcnt vmcnt(4)" ::: "memory");
        __builtin_amdgcn_s_barrier();
        __builtin_amdgcn_sched_barrier(0);
        GSTAGE((ks + 2) % 3, ks + 2);
        GTILE(ks);
    }
    asm volatile("s_waitcnt vmcnt(4)" ::: "memory");
    __builtin_amdgcn_s_barrier();
    GTILE(14);
    asm volatile("s_waitcnt vmcnt(0)" ::: "memory");
    __builtin_amdgcn_s_barrier();
    GTILE(15);

    // ---- epilogue: per-wave LDS stage (f16, pad-72 rows), coalesced stores ----
    __syncthreads();
    _Float16* eb = (_Float16*)gsm + wid * 4608;   // 64 x 72 f16 = 9216 B per wave
    const int rr = lane >> 3, cc = lane & 7;

    if (mat < 2) {
#pragma unroll
        for (int mi = 0; mi < 4; ++mi)
#pragma unroll
            for (int ni = 0; ni < 4; ++ni)
#pragma unroll
                for (int r = 0; r < 4; ++r)
                    eb[(mi * 16 + g * 4 + r) * 72 + ni * 16 + c] = (_Float16)acc[mi][ni][r];
        asm volatile("s_waitcnt lgkmcnt(0)" ::: "memory");
        _Float16* dstm = (mat == 0 ? qh : kh);
#pragma unroll
        for (int p = 0; p < 8; ++p) {
            int row = p * 8 + rr;
            f16x8 v = *(const f16x8*)&eb[row * 72 + cc * 8];
            *(f16x8*)(dstm + (size_t)(mtile * 128 + wm * 64 + row) * 512 +
                      ntile * 128 + wn * 64 + cc * 8) = v;
        }
    } else {
#pragma unroll
        for (int mi = 0; mi < 4; ++mi)
#pragma unroll
            for (int ni = 0; ni < 4; ++ni)
#pragma unroll
                for (int r = 0; r < 4; ++r)
                    eb[(ni * 16 + c) * 72 + mi * 16 + g * 4 + r] = (_Float16)acc[mi][ni][r];
        asm volatile("s_waitcnt lgkmcnt(0)" ::: "memory");
        const int h = ntile * 2 + wn;
        const int mbase = mtile * 128 + wm * 64;
        const int b = mbase >> 11, s0 = mbase & 2047;
#pragma unroll
        for (int p = 0; p < 8; ++p) {
            int d = p * 8 + rr;
            f16x8 v = *(const f16x8*)&eb[d * 72 + cc * 8];
            *(f16x8*)(vt + (((size_t)h * 4 + b) * 64 + d) * 2048 + s0 + cc * 8) = v;
        }
    }
}

// ---------------- kernel 3: flash attention + xcopy, 64-key tiles, staggered ---
__global__ __launch_bounds__(512, 4) void attn_kernel(
    const _Float16* __restrict__ qh, const _Float16* __restrict__ kh,
    const _Float16* __restrict__ vt, const float4* __restrict__ x4,
    float* __restrict__ out) {
    __shared__ __align__(16) char smem[65536];   // 2 sets x (K_A,V_A,K_B,V_B 8KB each)

    const int bid = blockIdx.x;
    const int xcd = bid & 7, idx = bid >> 3;
    const int hb = xcd * 4 + (idx >> 4);
    const int qblk = idx & 15;
    const int h = hb >> 2, b = hb & 3;
    const int tid = threadIdx.x, lane = tid & 63, wid = tid >> 6;
    const int qg = wid & 3, half = wid >> 2;
    const int q = lane & 31, hi = lane >> 5;

    // ---- xcopy slice ----
    {
        float4* xd = (float4*)(out + 4194304) + (size_t)bid * 2048;
        const float4* xs = x4 + (size_t)bid * 2048;
#pragma unroll
        for (int i = 0; i < 4; ++i) xd[i * 512 + tid] = xs[i * 512 + tid];
    }

    const int qrow0 = qblk * 128 + qg * 32;
    const _Float16* qp = qh + ((size_t)b * 2048 + qrow0) * 512 + h * 64;
    const _Float16* kp = kh + (size_t)b * 2048 * 512 + h * 64;
    const _Float16* vp = vt + (size_t)hb * 64 * 2048;

    const int srow = tid >> 3;
    const int ssw = (tid & 7) ^ ((srow ^ (srow >> 3)) & 7);

    auto STAGE = [&](int i) {
        char* base = smem + (i & 1) * 32768;
        GLD16(kp + ((size_t)(i * 64 + srow) * 512) + ssw * 8, (_Float16*)(base) + tid * 8);
        GLD16(vp + (size_t)srow * 2048 + i * 64 + ssw * 8, (_Float16*)(base + 8192) + tid * 8);
        GLD16(kp + ((size_t)((16 + i) * 64 + srow) * 512) + ssw * 8, (_Float16*)(base + 16384) + tid * 8);
        GLD16(vp + (size_t)srow * 2048 + (16 + i) * 64 + ssw * 8, (_Float16*)(base + 24576) + tid * 8);
    };

    f16x8 aQ[4];
#pragma unroll
    for (int kc = 0; kc < 4; ++kc)
        aQ[kc] = *(const f16x8*)(qp + (size_t)q * 512 + kc * 16 + hi * 8);

    float mrow = -1e30f, lrow = 0.f;
    f32x16 o0, o1;
#pragma unroll
    for (int i = 0; i < 16; ++i) { o0[i] = 0.f; o1[i] = 0.f; }

    const h16x2 ONE2 = {(__fp16)1.0f, (__fp16)1.0f};
    const int swr0 = (q ^ (q >> 3)) & 7;
    const int swr1 = ((32 + q) ^ ((32 + q) >> 3)) & 7;

    auto KPTR = [&](int t) {
        return (const _Float16*)(smem + (t & 1) * 32768 + half * 16384);
    };

    auto QKT2 = [&](const _Float16* kb, f32x16& s0, f32x16& s1) {
        f32x16 z0, z1;
#pragma unroll
        for (int i = 0; i < 16; ++i) { z0[i] = 0.f; z1[i] = 0.f; }
        __builtin_amdgcn_s_setprio(1);
#pragma unroll
        for (int kc = 0; kc < 4; ++kc) {
            f16x8 ak0 = *(const f16x8*)&kb[q * 64 + (((2 * kc + hi) ^ swr0) * 8)];
            f16x8 ak1 = *(const f16x8*)&kb[(32 + q) * 64 + (((2 * kc + hi) ^ swr1) * 8)];
            z0 = __builtin_amdgcn_mfma_f32_32x32x16_f16(ak0, aQ[kc], z0, 0, 0, 0);
            z1 = __builtin_amdgcn_mfma_f32_32x32x16_f16(ak1, aQ[kc], z1, 0, 0, 0);
        }
        __builtin_amdgcn_s_setprio(0);
        s0 = z0; s1 = z1;
    };

    auto SMPV2 = [&](f32x16& s0, f32x16& s1, const _Float16* vb) {
        float pm;
        {
            float m0 = fmaxf(fmaxf(fmaxf(s0[0], s0[1]), s0[2]), s0[3]);
            float m1 = fmaxf(fmaxf(fmaxf(s0[4], s0[5]), s0[6]), s0[7]);
            float m2 = fmaxf(fmaxf(fmaxf(s0[8], s0[9]), s0[10]), s0[11]);
            float m3 = fmaxf(fmaxf(fmaxf(s0[12], s0[13]), s0[14]), s0[15]);
            float m4 = fmaxf(fmaxf(fmaxf(s1[0], s1[1]), s1[2]), s1[3]);
            float m5 = fmaxf(fmaxf(fmaxf(s1[4], s1[5]), s1[6]), s1[7]);
            float m6 = fmaxf(fmaxf(fmaxf(s1[8], s1[9]), s1[10]), s1[11]);
            float m7 = fmaxf(fmaxf(fmaxf(s1[12], s1[13]), s1[14]), s1[15]);
            float t0 = fmaxf(fmaxf(m0, m1), m2);
            float t1 = fmaxf(fmaxf(m3, m4), m5);
            float t2 = fmaxf(m6, m7);
            pm = fmaxf(fmaxf(t0, t1), t2);
        }
        pm = fmaxf(pm, __shfl_xor(pm, 32));
        if (__any(pm > mrow + 8.0f)) {
            const float nm = fmaxf(mrow, pm);
            const float e = __builtin_amdgcn_exp2f((mrow - nm) * LOG2E);
            mrow = nm;
            lrow *= e;
            o0 *= e;
            o1 *= e;
        }
        const float nm2 = mrow * LOG2E;

#pragma unroll
        for (int i = 0; i < 16; ++i)
            s0[i] = __builtin_amdgcn_exp2f(fmaf(s0[i], LOG2E, -nm2));
#pragma unroll
        for (int i = 0; i < 16; ++i)
            s1[i] = __builtin_amdgcn_exp2f(fmaf(s1[i], LOG2E, -nm2));

        f16x8 pf[4];
        float rsA = 0.f, rsB = 0.f;
#pragma unroll
        for (int kb2 = 0; kb2 < 2; ++kb2) {
            const f32x16& sv = kb2 ? s1 : s0;
            h16x2 p0 = __builtin_amdgcn_cvt_pkrtz(sv[0], sv[1]);
            h16x2 p1 = __builtin_amdgcn_cvt_pkrtz(sv[2], sv[3]);
            h16x2 p2 = __builtin_amdgcn_cvt_pkrtz(sv[4], sv[5]);
            h16x2 p3 = __builtin_amdgcn_cvt_pkrtz(sv[6], sv[7]);
            h16x2 p4 = __builtin_amdgcn_cvt_pkrtz(sv[8], sv[9]);
            h16x2 p5 = __builtin_amdgcn_cvt_pkrtz(sv[10], sv[11]);
            h16x2 p6 = __builtin_amdgcn_cvt_pkrtz(sv[12], sv[13]);
            h16x2 p7 = __builtin_amdgcn_cvt_pkrtz(sv[14], sv[15]);
            rsA = __builtin_amdgcn_fdot2(p0, ONE2, rsA, false);
            rsB = __builtin_amdgcn_fdot2(p1, ONE2, rsB, false);
            rsA = __builtin_amdgcn_fdot2(p2, ONE2, rsA, false);
            rsB = __builtin_amdgcn_fdot2(p3, ONE2, rsB, false);
            rsA = __builtin_amdgcn_fdot2(p4, ONE2, rsA, false);
            rsB = __builtin_amdgcn_fdot2(p5, ONE2, rsB, false);
            rsA = __builtin_amdgcn_fdot2(p6, ONE2, rsA, false);
            rsB = __builtin_amdgcn_fdot2(p7, ONE2, rsB, false);
            unsigned t0 = __builtin_bit_cast(unsigned, p0);
            unsigned t1 = __builtin_bit_cast(unsigned, p1);
            unsigned t2 = __builtin_bit_cast(unsigned, p2);
            unsigned t3 = __builtin_bit_cast(unsigned, p3);
            unsigned t4 = __builtin_bit_cast(unsigned, p4);
            unsigned t5 = __builtin_bit_cast(unsigned, p5);
            unsigned t6 = __builtin_bit_cast(unsigned, p6);
            unsigned t7 = __builtin_bit_cast(unsigned, p7);
            asm volatile("v_permlane32_swap_b32 %0, %1" : "+v"(t0), "+v"(t2));
            asm volatile("v_permlane32_swap_b32 %0, %1" : "+v"(t1), "+v"(t3));
            asm volatile("v_permlane32_swap_b32 %0, %1" : "+v"(t4), "+v"(t6));
            asm volatile("v_permlane32_swap_b32 %0, %1" : "+v"(t5), "+v"(t7));
            uint4 u0; u0.x = t0; u0.y = t1; u0.z = t2; u0.w = t3;
            uint4 u1; u1.x = t4; u1.y = t5; u1.z = t6; u1.w = t7;
            pf[2 * kb2 + 0] = __builtin_bit_cast(f16x8, u0);
            pf[2 * kb2 + 1] = __builtin_bit_cast(f16x8, u1);
        }
        lrow += rsA + rsB;

        __builtin_amdgcn_s_setprio(1);
#pragma unroll
        for (int ck = 0; ck < 4; ++ck) {
            f16x8 av0 = *(const f16x8*)&vb[q * 64 + (((2 * ck + hi) ^ swr0) * 8)];
            f16x8 av1 = *(const f16x8*)&vb[(32 + q) * 64 + (((2 * ck + hi) ^ swr1) * 8)];
            o0 = __builtin_amdgcn_mfma_f32_32x32x16_f16(av0, pf[ck], o0, 0, 0, 0);
            o1 = __builtin_amdgcn_mfma_f32_32x32x16_f16(av1, pf[ck], o1, 0, 0, 0);
        }
        __builtin_amdgcn_s_setprio(0);
    };

#define WAITBAR() do { \
    asm volatile("s_waitcnt vmcnt(0)" ::: "memory"); \
    __builtin_amdgcn_s_barrier(); \
    __builtin_amdgcn_sched_barrier(0); \
} while (0)

    f32x16 s0, s1;
    STAGE(0);
    if (half == 0) {
#pragma unroll 1
        for (int t = 0; t < 16; ++t) {
            WAITBAR();
            if (t < 15) STAGE(t + 1);
            QKT2(KPTR(t), s0, s1);
            SMPV2(s0, s1, KPTR(t) + 4096);
        }
    } else {
        WAITBAR();
        STAGE(1);
        QKT2(KPTR(0), s0, s1);
#pragma unroll 1
        for (int t = 1; t < 16; ++t) {
            SMPV2(s0, s1, KPTR(t - 1) + 4096);
            WAITBAR();
            if (t < 15) STAGE(t + 1);
            QKT2(KPTR(t), s0, s1);
        }
        SMPV2(s0, s1, KPTR(15) + 4096);
    }

    // ---- flash-decode merge: half B hands (o, m, l) to half A via LDS ----
    lrow += __shfl_xor(lrow, 32);
    __builtin_amdgcn_s_barrier();

    float* xg = (float*)smem + qg * 2112;
    if (half) {
#pragma unroll
        for (int i = 0; i < 16; ++i) {
            xg[i * 64 + lane] = o0[i];
            xg[(16 + i) * 64 + lane] = o1[i];
        }
        if (!hi) { xg[2048 + q] = mrow; xg[2080 + q] = lrow; }
    }
    __syncthreads();
    if (!half) {
        const float m_b = xg[2048 + q], l_b = xg[2080 + q];
        const float m = fmaxf(mrow, m_b);
        const float e_a = __builtin_amdgcn_exp2f((mrow - m) * LOG2E);
        const float e_b = __builtin_amdgcn_exp2f((m_b - m) * LOG2E);
        const float inv = 1.0f / (lrow * e_a + l_b * e_b);
        const float sa = e_a * inv, sb = e_b * inv;
#pragma unroll
        for (int i = 0; i < 16; ++i) {
            o0[i] = o0[i] * sa + xg[i * 64 + lane] * sb;
            o1[i] = o1[i] * sa + xg[(16 + i) * 64 + lane] * sb;
        }
        asm volatile("s_waitcnt lgkmcnt(0)" ::: "memory");
#pragma unroll
        for (int i = 0; i < 16; ++i) {
            int dr = (i & 3) + 8 * (i >> 2) + 4 * hi;
            xg[dr * 33 + q] = o0[i];
            xg[(32 + dr) * 33 + q] = o1[i];
        }
        __builtin_amdgcn_s_waitcnt(0);
        const int d0c = (lane & 15) * 4;
#pragma unroll
        for (int i2 = 0; i2 < 8; ++i2) {
            int qr = 4 * i2 + (lane >> 4);
            float4 v;
            v.x = xg[(d0c + 0) * 33 + qr];
            v.y = xg[(d0c + 1) * 33 + qr];
            v.z = xg[(d0c + 2) * 33 + qr];
            v.w = xg[(d0c + 3) * 33 + qr];
            *(float4*)(out + ((size_t)b * 2048 + qrow0 + qr) * 512 + h * 64 + d0c) = v;
        }
    }
#undef WAITBAR
}

extern "C" void kernel_launch(void* const* d_in, const int* in_sizes, int n_in,
                              void* d_out, int out_size, void* d_ws, size_t ws_size,
                              hipStream_t stream) {
    const float* x = (const float*)d_in[0];
    const float* Wq = (const float*)d_in[1];
    const float* Wk = (const float*)d_in[2];
    const float* Wv = (const float*)d_in[3];
    float* out = (float*)d_out;

    char* ws = (char*)d_ws;
    _Float16* xh = (_Float16*)ws;                          // 8 MB
    _Float16* wt = (_Float16*)(ws + (size_t)(10u << 20));  // 1.5 MB
    _Float16* qh = (_Float16*)(ws + (size_t)(12u << 20));  // 8 MB
    _Float16* kh = (_Float16*)(ws + (size_t)(20u << 20));  // 8 MB
    _Float16* vt = (_Float16*)(ws + (size_t)(28u << 20));  // 8 MB

    cvt_all_kernel<<<2240, 256, 0, stream>>>((const float4*)x, (f16x8*)xh,
                                             Wq, Wk, Wv, wt);
    gemm_qkv<<<768, 256, 0, stream>>>(xh, wt, qh, kh, vt);
    attn_kernel<<<512, 512, 0, stream>>>(qh, kh, vt, (const float4*)x, out);
}